// Round 9
// baseline (623.584 us; speedup 1.0000x reference)
//
#include <hip/hip_runtime.h>

#define L_SEQ   2048
#define BATCH   2
#define NDIM    1024
#define NHEADS  16
#define HD      64
#define DSTATE  16
#define DCONV   4
#define DINNER  2048
#define DTRANK  64
#define CHUNK   32
#define NCHUNK  (L_SEQ / CHUNK)   // 64
#define SPLIT_KT 8                // KV tiles per attention split

typedef short  short8  __attribute__((ext_vector_type(8)));
typedef float  floatx4 __attribute__((ext_vector_type(4)));

#define AS1 __attribute__((address_space(1)))
#define AS3 __attribute__((address_space(3)))

__device__ __forceinline__ float bf2f(ushort u) {
    union { uint i; float f; } v; v.i = ((uint)u) << 16; return v.f;
}
__device__ __forceinline__ ushort f2bf(float f) {
    uint x = __float_as_uint(f);
    uint r = (x + 0x7fffu + ((x >> 16) & 1u)) >> 16;
    return (ushort)r;
}
__device__ __forceinline__ float silu_f(float x) {
    return x / (1.f + __expf(-x));
}
__device__ __forceinline__ void gld_lds16(const void* g, void* l) {
    __builtin_amdgcn_global_load_lds((const AS1 uint*)g, (AS3 uint*)l, 16, 0, 0);
}

// ---------------------------------------------------------------------------
// dtype probe: flag=1 -> input arrays are float32 (bit-pattern heuristic).
// ---------------------------------------------------------------------------
__global__ void probe_kernel(const ushort* __restrict__ x, int* __restrict__ flag) {
    __shared__ int cnt;
    if (threadIdx.x == 0) cnt = 0;
    __syncthreads();
    ushort w = x[threadIdx.x];
    int e = (w >> 7) & 0xff;
    if (w != 0 && (e < 100 || e > 140)) atomicAdd(&cnt, 1);
    __syncthreads();
    if (threadIdx.x == 0) *flag = (cnt >= 16) ? 1 : 0;
}

// ---------------------------------------------------------------------------
// dtype-agnostic convert: src is f32 if *flag else bf16 bits.
// ---------------------------------------------------------------------------
__global__ __launch_bounds__(256) void cvt_kernel(
    const void* __restrict__ src, ushort* __restrict__ db,
    float* __restrict__ df, int n, const int* __restrict__ flag)
{
    int i = blockIdx.x * 256 + threadIdx.x;
    if (i >= n) return;
    float v = (*flag) ? ((const float*)src)[i] : bf2f(((const ushort*)src)[i]);
    if (db) db[i] = f2bf(v);
    if (df) df[i] = v;
}

// ---------------------------------------------------------------------------
// one-launch conversion of all small parameter arrays -> f32.
// ---------------------------------------------------------------------------
__device__ __forceinline__ float cvt_one(const void* s, int i, int f) {
    return f ? ((const float*)s)[i] : bf2f(((const ushort*)s)[i]);
}
__global__ __launch_bounds__(256) void cvt_small(
    const void* bqkv, const void* bao, const void* convw, const void* convb,
    const void* bdt, const void* Alog, const void* Dp,
    float* __restrict__ bqkv_f, float* __restrict__ bao_f,
    float* __restrict__ convw_f, float* __restrict__ convb_f,
    float* __restrict__ bdt_f, float* __restrict__ Alog_f,
    float* __restrict__ Dp_f, const int* __restrict__ flag)
{
    int i = blockIdx.x * 256 + threadIdx.x;
    const int f = *flag;
    if      (i < 1152)   bqkv_f[i]          = cvt_one(bqkv,  i,          f);
    else if (i < 2176)   bao_f[i - 1152]    = cvt_one(bao,   i - 1152,   f);
    else if (i < 10368)  convw_f[i - 2176]  = cvt_one(convw, i - 2176,   f);
    else if (i < 12416)  convb_f[i - 10368] = cvt_one(convb, i - 10368,  f);
    else if (i < 14464)  bdt_f[i - 12416]   = cvt_one(bdt,   i - 12416,  f);
    else if (i < 47232)  Alog_f[i - 14464]  = cvt_one(Alog,  i - 14464,  f);
    else if (i < 49280)  Dp_f[i - 47232]    = cvt_one(Dp,    i - 47232,  f);
}

// ---------------------------------------------------------------------------
// convert + transpose: src (K,N) -> dst (N,K) bf16. K,N multiples of 32.
// ---------------------------------------------------------------------------
__global__ __launch_bounds__(256) void cvt_t_kernel(
    const void* __restrict__ src, ushort* __restrict__ dst,
    int K, int N, const int* __restrict__ flag)
{
    __shared__ float tile[32][33];
    const int tx = threadIdx.x & 31, ty = threadIdx.x >> 5;
    const int n0 = blockIdx.x * 32, k0 = blockIdx.y * 32;
    const int f = *flag;
    #pragma unroll
    for (int r = 0; r < 4; ++r) {
        int k = k0 + ty + r * 8;
        size_t o = (size_t)k * N + n0 + tx;
        tile[ty + r * 8][tx] = f ? ((const float*)src)[o] : bf2f(((const ushort*)src)[o]);
    }
    __syncthreads();
    #pragma unroll
    for (int r = 0; r < 4; ++r) {
        int n = n0 + ty + r * 8;
        dst[(size_t)n * K + k0 + tx] = f2bf(tile[tx][ty + r * 8]);
    }
}

// ---------------------------------------------------------------------------
// MFMA GEMM: 128x128 tile, BK=64, XOR k-slot swizzle, XCD-aware grid:
// m-block = blockIdx.x (gridDim.x = M/128, mult of 8) so all n-blocks of one
// m-strip share linear-id mod 8 -> same XCD -> A-strip cached in that L2.
// ---------------------------------------------------------------------------
__global__ __launch_bounds__(256) void gemm128(
    const ushort* __restrict__ A, int lda,
    const ushort* __restrict__ Wt,
    const float* __restrict__ bias,
    const ushort* __restrict__ resb,
    ushort* __restrict__ outb, float* __restrict__ outf,
    const int* __restrict__ dtflag,
    int N, int K, int act, int klen, float* __restrict__ psum)
{
    __shared__ __align__(16) ushort As[128 * 64];
    __shared__ __align__(16) ushort Bs[128 * 64];

    const int tid  = threadIdx.x;
    const int wave = tid >> 6;
    const int lane = tid & 63;
    const int wm = (wave >> 1) * 64;
    const int wn = (wave & 1) * 64;
    const int fm = lane & 15;
    const int quad = lane >> 4;
    const int m0 = blockIdx.x * 128;   // XCD-aware: m from x
    const int n0 = blockIdx.y * 128;

    floatx4 acc[4][4];
    #pragma unroll
    for (int i = 0; i < 4; ++i)
        #pragma unroll
        for (int j = 0; j < 4; ++j) acc[i][j] = (floatx4){0.f, 0.f, 0.f, 0.f};

    int rowv[4], kgv[4];
    #pragma unroll
    for (int j = 0; j < 4; ++j) {
        int c = wave * 256 + j * 64 + lane;
        rowv[j] = c >> 3;
        kgv[j]  = (((c & 7) ^ ((c >> 3) & 7))) * 8;
    }

    const int kbeg = psum ? (blockIdx.z * klen) : 0;
    const int kend = kbeg + klen;

    for (int k0 = kbeg; k0 < kend; k0 += 64) {
        #pragma unroll
        for (int j = 0; j < 4; ++j)
            gld_lds16(A  + (size_t)(m0 + rowv[j]) * lda + k0 + kgv[j],
                      &As[(wave * 256 + j * 64) * 8]);
        #pragma unroll
        for (int j = 0; j < 4; ++j)
            gld_lds16(Wt + (size_t)(n0 + rowv[j]) * K   + k0 + kgv[j],
                      &Bs[(wave * 256 + j * 64) * 8]);
        __syncthreads();

        #pragma unroll
        for (int h = 0; h < 2; ++h) {
            short8 af[4], bf[4];
            #pragma unroll
            for (int i = 0; i < 4; ++i) {
                int row = wm + i * 16 + fm;
                int slot = (h * 4 + quad) ^ (row & 7);
                af[i] = *(const short8*)&As[row * 64 + slot * 8];
            }
            #pragma unroll
            for (int j = 0; j < 4; ++j) {
                int row = wn + j * 16 + fm;
                int slot = (h * 4 + quad) ^ (row & 7);
                bf[j] = *(const short8*)&Bs[row * 64 + slot * 8];
            }
            #pragma unroll
            for (int i = 0; i < 4; ++i)
                #pragma unroll
                for (int j = 0; j < 4; ++j)
                    acc[i][j] = __builtin_amdgcn_mfma_f32_16x16x32_bf16(af[i], bf[j], acc[i][j], 0, 0, 0);
        }
        __syncthreads();
    }

    if (psum) {
        float* po = psum + (size_t)blockIdx.z * ((size_t)gridDim.x * 128) * N;
        #pragma unroll
        for (int j = 0; j < 4; ++j) {
            int col = n0 + wn + j * 16 + fm;
            #pragma unroll
            for (int i = 0; i < 4; ++i) {
                int rowb = m0 + wm + i * 16 + quad * 4;
                #pragma unroll
                for (int r = 0; r < 4; ++r)
                    po[(size_t)(rowb + r) * N + col] = acc[i][j][r];
            }
        }
        return;
    }

    const int flagv = dtflag ? *dtflag : 0;
    #pragma unroll
    for (int j = 0; j < 4; ++j) {
        int col = n0 + wn + j * 16 + fm;
        float bvv = bias ? bias[col] : 0.f;
        #pragma unroll
        for (int i = 0; i < 4; ++i) {
            int rowb = m0 + wm + i * 16 + quad * 4;
            #pragma unroll
            for (int r = 0; r < 4; ++r) {
                float v = acc[i][j][r] + bvv;
                if (act == 1) v = fmaxf(v, 0.f) + log1pf(__expf(-fabsf(v)));
                size_t o = (size_t)(rowb + r) * N + col;
                if (resb) v += bf2f(resb[o]);
                if (dtflag) {
                    if (flagv) outf[o] = v; else outb[o] = f2bf(v);
                } else {
                    if (outb) outb[o] = f2bf(v);
                    if (outf) outf[o] = v;
                }
            }
        }
    }
}

// ---------------------------------------------------------------------------
// combine split-K partials (4096 x 128 padded) -> xdbl bf16 (stride 96).
// ---------------------------------------------------------------------------
__global__ __launch_bounds__(256) void combine_xdbl(
    const float* __restrict__ psum, ushort* __restrict__ xdbl)
{
    int idx = blockIdx.x * 256 + threadIdx.x;
    int row = idx / 96, col = idx - row * 96;
    float s = 0.f;
    #pragma unroll
    for (int z = 0; z < 8; ++z)
        s += psum[(size_t)z * 4096 * 128 + row * 128 + col];
    xdbl[idx] = f2bf(s);
}

// ---------------------------------------------------------------------------
// Flash MQA attention, split-KV, static-max softmax.
// ---------------------------------------------------------------------------
__global__ __launch_bounds__(256) void flash_attn_split(
    const ushort* __restrict__ qkv, ushort* __restrict__ att,
    ushort* __restrict__ partO, float* __restrict__ partL)
{
    __shared__ __align__(16) ushort Ks[64 * 72];
    __shared__ __align__(16) ushort Vt[64 * 72];
    __shared__ __align__(16) ushort Ps[4][32 * 72];

    const int tile = blockIdx.x;
    const int hg   = blockIdx.y;
    const int zz   = blockIdx.z;
    const int b = zz >> 2, s = zz & 3;
    const int q0 = tile * 32;
    const int nkv = (q0 >> 6) + 1;
    const int nsplit = (nkv + SPLIT_KT - 1) / SPLIT_KT;
    if (s >= nsplit) return;
    const int kt0 = s * SPLIT_KT;
    const int kt1 = (nkv < kt0 + SPLIT_KT) ? nkv : (kt0 + SPLIT_KT);

    const int tid  = threadIdx.x;
    const int wave = tid >> 6;
    const int lane = tid & 63;
    const int fm   = lane & 15;
    const int quad = lane >> 4;
    const int h    = hg * 4 + wave;

    const int srow = tid >> 3;
    const int scol = (tid & 7) * 8;
    const int vsw  = (tid & 7) << 3;

    short8 qf[2][2];
    #pragma unroll
    for (int i = 0; i < 2; ++i)
        #pragma unroll
        for (int kh = 0; kh < 2; ++kh)
            qf[i][kh] = *(const short8*)(qkv +
                (size_t)(b * L_SEQ + q0 + i * 16 + fm) * 1152 + h * HD + kh * 32 + quad * 8);

    floatx4 acc[2][4];
    float l_part[2][4];
    #pragma unroll
    for (int i = 0; i < 2; ++i) {
        #pragma unroll
        for (int j = 0; j < 4; ++j) acc[i][j] = (floatx4){0.f, 0.f, 0.f, 0.f};
        #pragma unroll
        for (int r = 0; r < 4; ++r) l_part[i][r] = 0.f;
    }

    for (int kt = kt0; kt < kt1; ++kt) {
        const int kv0 = kt * 64;
        __syncthreads();
        #pragma unroll
        for (int pass = 0; pass < 2; ++pass) {
            int row = srow + pass * 32;
            const ushort* kp = qkv + (size_t)(b * L_SEQ + kv0 + row) * 1152 + NDIM + scol;
            *(short8*)&Ks[row * 72 + scol] = *(const short8*)kp;
            short8 t = *(const short8*)(kp + HD);
            int mw = row ^ vsw;
            #pragma unroll
            for (int i2 = 0; i2 < 8; ++i2) Vt[(scol + i2) * 72 + mw] = (ushort)t[i2];
        }
        __syncthreads();

        floatx4 sp[2][4];
        #pragma unroll
        for (int j = 0; j < 4; ++j) {
            short8 kf0 = *(const short8*)&Ks[(j * 16 + fm) * 72 + quad * 8];
            short8 kf1 = *(const short8*)&Ks[(j * 16 + fm) * 72 + 32 + quad * 8];
            #pragma unroll
            for (int i = 0; i < 2; ++i) {
                floatx4 z = (floatx4){0.f, 0.f, 0.f, 0.f};
                z = __builtin_amdgcn_mfma_f32_16x16x32_bf16(qf[i][0], kf0, z, 0, 0, 0);
                z = __builtin_amdgcn_mfma_f32_16x16x32_bf16(qf[i][1], kf1, z, 0, 0, 0);
                sp[i][j] = z;
            }
        }

        const bool diag = (kt == nkv - 1);
        #pragma unroll
        for (int i = 0; i < 2; ++i)
            #pragma unroll
            for (int j = 0; j < 4; ++j) {
                int col = kv0 + j * 16 + fm;
                #pragma unroll
                for (int r = 0; r < 4; ++r) {
                    float p = __expf(sp[i][j][r] * 0.125f);
                    if (diag) {
                        int rowg = q0 + i * 16 + quad * 4 + r;
                        if (col > rowg) p = 0.f;
                    }
                    sp[i][j][r] = p;
                    l_part[i][r] += p;
                }
            }

        #pragma unroll
        for (int i = 0; i < 2; ++i)
            #pragma unroll
            for (int j = 0; j < 4; ++j)
                #pragma unroll
                for (int r = 0; r < 4; ++r)
                    Ps[wave][(i * 16 + quad * 4 + r) * 72 + j * 16 + fm] = f2bf(sp[i][j][r]);

        short8 pf[2][2];
        #pragma unroll
        for (int i = 0; i < 2; ++i) {
            pf[i][0] = *(const short8*)&Ps[wave][(i * 16 + fm) * 72 + quad * 8];
            pf[i][1] = *(const short8*)&Ps[wave][(i * 16 + fm) * 72 + 32 + quad * 8];
        }

        #pragma unroll
        for (int dj = 0; dj < 4; ++dj) {
            int d = dj * 16 + fm;
            int sw8 = ((d >> 3) & 7) << 3;
            short8 vf0 = *(const short8*)&Vt[d * 72 + ((quad * 8) ^ sw8)];
            short8 vf1 = *(const short8*)&Vt[d * 72 + ((32 + quad * 8) ^ sw8)];
            #pragma unroll
            for (int i = 0; i < 2; ++i) {
                acc[i][dj] = __builtin_amdgcn_mfma_f32_16x16x32_bf16(pf[i][0], vf0, acc[i][dj], 0, 0, 0);
                acc[i][dj] = __builtin_amdgcn_mfma_f32_16x16x32_bf16(pf[i][1], vf1, acc[i][dj], 0, 0, 0);
            }
        }
    }

    float l_red[2][4];
    #pragma unroll
    for (int i = 0; i < 2; ++i)
        #pragma unroll
        for (int r = 0; r < 4; ++r) {
            float rs = l_part[i][r];
            rs += __shfl_xor(rs, 1, 16);
            rs += __shfl_xor(rs, 2, 16);
            rs += __shfl_xor(rs, 4, 16);
            rs += __shfl_xor(rs, 8, 16);
            l_red[i][r] = rs;
        }

    if (nsplit == 1) {
        #pragma unroll
        for (int i = 0; i < 2; ++i) {
            float inv[4];
            #pragma unroll
            for (int r = 0; r < 4; ++r) inv[r] = 1.f / l_red[i][r];
            #pragma unroll
            for (int dj = 0; dj < 4; ++dj)
                #pragma unroll
                for (int r = 0; r < 4; ++r) {
                    int q = q0 + i * 16 + quad * 4 + r;
                    att[(size_t)(b * L_SEQ + q) * NDIM + h * HD + dj * 16 + fm] =
                        f2bf(acc[i][dj][r] * inv[r]);
                }
        }
    } else {
        size_t pbase = ((size_t)((s * 2 + b) * 16 + h)) * L_SEQ;
        #pragma unroll
        for (int i = 0; i < 2; ++i)
            #pragma unroll
            for (int dj = 0; dj < 4; ++dj)
                #pragma unroll
                for (int r = 0; r < 4; ++r) {
                    int q = q0 + i * 16 + quad * 4 + r;
                    partO[(pbase + q) * 64 + dj * 16 + fm] = f2bf(acc[i][dj][r]);
                }
        if (fm == 0) {
            #pragma unroll
            for (int i = 0; i < 2; ++i)
                #pragma unroll
                for (int r = 0; r < 4; ++r)
                    partL[pbase + q0 + i * 16 + quad * 4 + r] = l_red[i][r];
        }
    }
}

// ---------------------------------------------------------------------------
// combine attention split partials for q >= 512.
// ---------------------------------------------------------------------------
__global__ __launch_bounds__(256) void attn_combine(
    const ushort* __restrict__ partO, const float* __restrict__ partL,
    ushort* __restrict__ att)
{
    int gid = blockIdx.x * 256 + threadIdx.x;
    int t8 = gid & 7;
    int row = gid >> 3;
    int q  = 512 + (row % 1536);
    int bh = row / 1536;
    int b = bh >> 4, h = bh & 15;
    int nsplit = (((q >> 5) >> 1) + 1 + SPLIT_KT - 1) / SPLIT_KT;

    float sum[8] = {0.f, 0.f, 0.f, 0.f, 0.f, 0.f, 0.f, 0.f};
    float L = 0.f;
    for (int s = 0; s < nsplit; ++s) {
        size_t pbase = ((size_t)((s * 2 + b) * 16 + h)) * L_SEQ + q;
        L += partL[pbase];
        short8 o = *(const short8*)&partO[pbase * 64 + t8 * 8];
        #pragma unroll
        for (int k = 0; k < 8; ++k) sum[k] += bf2f((ushort)o[k]);
    }
    float inv = 1.f / L;
    short8 outv;
    #pragma unroll
    for (int k = 0; k < 8; ++k) outv[k] = (short)f2bf(sum[k] * inv);
    *(short8*)&att[((size_t)(b * L_SEQ + q)) * NDIM + h * HD + t8 * 8] = outv;
}

// ---------------------------------------------------------------------------
// depthwise conv (window 4, left pad 3) + bias + silu.
// ---------------------------------------------------------------------------
__global__ __launch_bounds__(256) void conv_silu(
    const ushort* __restrict__ xr, const float* __restrict__ conv_w,
    const float* __restrict__ conv_b, ushort* __restrict__ u)
{
    const int idx = blockIdx.x * 256 + threadIdx.x;
    const int c  = idx & (DINNER - 1);
    const int bl = idx >> 11;
    const int l  = bl & (L_SEQ - 1);

    float acc = conv_b[c];
    #pragma unroll
    for (int j = 0; j < DCONV; ++j) {
        int ls = l - 3 + j;
        if (ls >= 0)
            acc += bf2f(xr[(size_t)(bl - 3 + j) * (2 * DINNER) + c]) * conv_w[c * DCONV + j];
    }
    u[idx] = f2bf(silu_f(acc));
}

// ---------------------------------------------------------------------------
// Chunked selective scan, phase 1.
// ---------------------------------------------------------------------------
__global__ __launch_bounds__(256) void scan_phase1(
    const ushort* __restrict__ delta, const ushort* __restrict__ u,
    const ushort* __restrict__ xdbl, const float* __restrict__ A_log,
    float* __restrict__ Hend, float* __restrict__ Sdt)
{
    const int idx = blockIdx.x * 256 + threadIdx.x;
    const int d = idx & (DINNER - 1);
    const int b = (idx >> 11) & (BATCH - 1);
    const int c = idx >> 12;

    float Av[DSTATE], h[DSTATE];
    #pragma unroll
    for (int n = 0; n < DSTATE; ++n) {
        Av[n] = -__expf(A_log[d * DSTATE + n]);
        h[n] = 0.f;
    }

    const int t0 = c * CHUNK;
    size_t bd = ((size_t)b * L_SEQ + t0) * DINNER + d;
    size_t bx = ((size_t)b * L_SEQ + t0) * 96 + DTRANK;
    float sdt = 0.f;

    for (int t = 0; t < CHUNK; ++t) {
        float dt = bf2f(delta[bd]);
        float uv = bf2f(u[bd]);
        sdt += dt;
        float du = dt * uv;
        short8 B0 = *(const short8*)&xdbl[bx];
        short8 B1 = *(const short8*)&xdbl[bx + 8];
        #pragma unroll
        for (int n = 0; n < 8; ++n)
            h[n] = __expf(dt * Av[n]) * h[n] + du * bf2f((ushort)B0[n]);
        #pragma unroll
        for (int n = 0; n < 8; ++n)
            h[8 + n] = __expf(dt * Av[8 + n]) * h[8 + n] + du * bf2f((ushort)B1[n]);
        bd += DINNER; bx += 96;
    }

    size_t ho = (((size_t)c * BATCH + b) * DINNER + d) * DSTATE;
    #pragma unroll
    for (int n = 0; n < DSTATE; n += 4)
        *(floatx4*)&Hend[ho + n] = (floatx4){h[n], h[n + 1], h[n + 2], h[n + 3]};
    Sdt[((size_t)c * BATCH + b) * DINNER + d] = sdt;
}

// ---------------------------------------------------------------------------
// phase 2: in-place exclusive combine over 64 chunks.
// ---------------------------------------------------------------------------
__global__ __launch_bounds__(256) void scan_phase2(
    float* __restrict__ H, const float* __restrict__ Sdt,
    const float* __restrict__ A_log)
{
    const int idx = blockIdx.x * 256 + threadIdx.x;
    const int n = idx & (DSTATE - 1);
    const int d = (idx >> 4) & (DINNER - 1);
    const int b = idx >> 15;

    const float Av = -__expf(A_log[d * DSTATE + n]);
    float hin = 0.f;
    for (int c = 0; c < NCHUNK; ++c) {
        size_t o  = (((size_t)c * BATCH + b) * DINNER + d) * DSTATE + n;
        float e   = H[o];
        float dAc = __expf(Av * Sdt[((size_t)c * BATCH + b) * DINNER + d]);
        H[o] = hin;
        hin = dAc * hin + e;
    }
}

// ---------------------------------------------------------------------------
// phase 3: redo chunk scan from Hin, emit y, fused ymod.
// ---------------------------------------------------------------------------
__global__ __launch_bounds__(256) void scan_phase3(
    const ushort* __restrict__ delta, const ushort* __restrict__ u,
    const ushort* __restrict__ xdbl, const float* __restrict__ A_log,
    const float* __restrict__ Hin, const float* __restrict__ Dp,
    const ushort* __restrict__ xr, ushort* __restrict__ yb)
{
    const int idx = blockIdx.x * 256 + threadIdx.x;
    const int d = idx & (DINNER - 1);
    const int b = (idx >> 11) & (BATCH - 1);
    const int c = idx >> 12;

    float Av[DSTATE], h[DSTATE];
    size_t ho = (((size_t)c * BATCH + b) * DINNER + d) * DSTATE;
    #pragma unroll
    for (int n = 0; n < DSTATE; n += 4) {
        floatx4 hv = *(const floatx4*)&Hin[ho + n];
        h[n] = hv[0]; h[n + 1] = hv[1]; h[n + 2] = hv[2]; h[n + 3] = hv[3];
    }
    #pragma unroll
    for (int n = 0; n < DSTATE; ++n)
        Av[n] = -__expf(A_log[d * DSTATE + n]);

    const float Dpd = Dp[d];
    const int t0 = c * CHUNK;
    size_t bd = ((size_t)b * L_SEQ + t0) * DINNER + d;
    size_t bx = ((size_t)b * L_SEQ + t0) * 96 + DTRANK;
    size_t br = ((size_t)b * L_SEQ + t0) * (2 * DINNER) + DINNER + d;

    for (int t = 0; t < CHUNK; ++t) {
        float dt = bf2f(delta[bd]);
        float uv = bf2f(u[bd]);
        float du = dt * uv;
        short8 B0 = *(const short8*)&xdbl[bx];
        short8 B1 = *(const short8*)&xdbl[bx + 8];
        short8 C0 = *(const short8*)&xdbl[bx + 16];
        short8 C1 = *(const short8*)&xdbl[bx + 24];
        float y = 0.f;
        #pragma unroll
        for (int n = 0; n < 8; ++n) {
            h[n] = __expf(dt * Av[n]) * h[n] + du * bf2f((ushort)B0[n]);
            y += h[n] * bf2f((ushort)C0[n]);
        }
        #pragma unroll
        for (int n = 0; n < 8; ++n) {
            h[8 + n] = __expf(dt * Av[8 + n]) * h[8 + n] + du * bf2f((ushort)B1[n]);
            y += h[8 + n] * bf2f((ushort)C1[n]);
        }
        float yv = y + uv * Dpd;
        float r  = bf2f(xr[br]);
        yb[bd] = f2bf(yv * silu_f(r));
        bd += DINNER; bx += 96; br += 2 * DINNER;
    }
}

// ---------------------------------------------------------------------------
extern "C" void kernel_launch(void* const* d_in, const int* in_sizes, int n_in,
                              void* d_out, int out_size, void* d_ws, size_t ws_size,
                              hipStream_t stream) {
    const void* x_raw      = d_in[0];
    const void* wqkv_raw   = d_in[1];
    const void* bqkv_raw   = d_in[2];
    const void* wao_raw    = d_in[3];
    const void* bao_raw    = d_in[4];
    const void* win_raw    = d_in[5];
    const void* convw_raw  = d_in[6];
    const void* convb_raw  = d_in[7];
    const void* wxp_raw    = d_in[8];
    const void* wdt_raw    = d_in[9];
    const void* bdt_raw    = d_in[10];
    const void* Alog_raw   = d_in[11];
    const void* Dp_raw     = d_in[12];
    const void* wout_raw   = d_in[13];

    const int M = BATCH * L_SEQ;  // 4096

    char* p = (char*)d_ws;
    size_t off = 0;
    auto A_ = [&](size_t bytes) { void* q = p + off; off += (bytes + 255) & ~255ull; return q; };

    ushort* x_b    = (ushort*)A_((size_t)M * NDIM * 2);
    ushort* wqkv_t = (ushort*)A_((size_t)NDIM * 1152 * 2);
    ushort* wao_t  = (ushort*)A_((size_t)NDIM * NDIM * 2);
    ushort* win_t  = (ushort*)A_((size_t)NDIM * 4096 * 2);
    float*  psum   = (float*)x_b;
    ushort* yb     = x_b;
    float*  Sdt    = (float*)(x_b + (size_t)M * DINNER);

    ushort* qkv    = (ushort*)A_((size_t)M * 1152 * 2);
    ushort* att    = (ushort*)A_((size_t)M * NDIM * 2);
    float*  Hend   = (float*)qkv;

    ushort* delta_b = (ushort*)A_((size_t)M * DINNER * 2);

    ushort* wxp_t  = (ushort*)A_((size_t)128 * DINNER * 2);
    ushort* wdt_t  = (ushort*)A_((size_t)DTRANK * DINNER * 2);
    ushort* wout_t = (ushort*)A_((size_t)DINNER * NDIM * 2);
    float*  bqkv_f = (float*)A_(1152 * 4);
    float*  bao_f  = (float*)A_(NDIM * 4);
    float*  convw_f= (float*)A_((size_t)DINNER * DCONV * 4);
    float*  convb_f= (float*)A_(DINNER * 4);
    float*  bdt_f  = (float*)A_(DINNER * 4);
    float*  Alog_f = (float*)A_((size_t)DINNER * DSTATE * 4);
    float*  Dp_f   = (float*)A_(DINNER * 4);
    int*    flag   = (int*)A_(256);
    ushort* x1b    = (ushort*)A_((size_t)M * NDIM * 2);
    ushort* xr     = (ushort*)A_((size_t)M * 4096 * 2);
    ushort* u      = (ushort*)A_((size_t)M * DINNER * 2);
    ushort* xdbl   = (ushort*)A_((size_t)M * 96 * 2);

    ushort* partO = xr;
    float*  partL = (float*)u;

    dim3 blk(256);
    auto cvt_t = [&](const void* src, ushort* dst, int K, int N) {
        cvt_t_kernel<<<dim3(N / 32, K / 32), blk, 0, stream>>>(src, dst, K, N, flag);
    };

    // 0. dtype probe + canonicalize (+ transpose weights)
    probe_kernel<<<dim3(1), blk, 0, stream>>>((const ushort*)x_raw, flag);
    cvt_kernel<<<dim3(M * NDIM / 256), blk, 0, stream>>>(x_raw, x_b, nullptr, M * NDIM, flag);
    cvt_t(wqkv_raw, wqkv_t, NDIM, 1152);
    cvt_t(wao_raw,  wao_t,  NDIM, NDIM);
    cvt_t(win_raw,  win_t,  NDIM, 4096);
    cvt_t(wxp_raw,  wxp_t,  DINNER, 96);
    hipMemsetAsync(wxp_t + (size_t)96 * DINNER, 0, (size_t)32 * DINNER * 2, stream);
    cvt_t(wdt_raw,  wdt_t,  DTRANK, DINNER);
    cvt_t(wout_raw, wout_t, DINNER, NDIM);
    cvt_small<<<dim3((49280 + 255) / 256), blk, 0, stream>>>(
        bqkv_raw, bao_raw, convw_raw, convb_raw, bdt_raw, Alog_raw, Dp_raw,
        bqkv_f, bao_f, convw_f, convb_f, bdt_f, Alog_f, Dp_f, flag);

    // 1. qkv = x @ wqkv + bqkv   (grid: m-blocks in x)
    gemm128<<<dim3(M / 128, 1152 / 128), blk, 0, stream>>>(
        x_b, NDIM, wqkv_t, bqkv_f, nullptr, qkv, nullptr, nullptr, 1152, NDIM, 0, NDIM, nullptr);

    // 2. flash attention (split-KV) + combine
    flash_attn_split<<<dim3(L_SEQ / 32, NHEADS / 4, BATCH * 4), blk, 0, stream>>>(
        qkv, att, partO, partL);
    attn_combine<<<dim3(1536), blk, 0, stream>>>(partO, partL, att);

    // 3. x1 = att @ w_ao + b_ao + x
    gemm128<<<dim3(M / 128, NDIM / 128), blk, 0, stream>>>(
        att, NDIM, wao_t, bao_f, x_b, x1b, nullptr, nullptr, NDIM, NDIM, 0, NDIM, nullptr);

    // 4. xr = x1 @ w_in
    gemm128<<<dim3(M / 128, 4096 / 128), blk, 0, stream>>>(
        x1b, NDIM, win_t, nullptr, nullptr, xr, nullptr, nullptr, 4096, NDIM, 0, NDIM, nullptr);

    // 5. conv + silu -> u
    conv_silu<<<dim3(M * DINNER / 256), blk, 0, stream>>>(xr, convw_f, convb_f, u);

    // 6. xdbl = u @ w_xproj  (split-K=8 over padded N=128, f32 partials)
    gemm128<<<dim3(M / 128, 1, 8), blk, 0, stream>>>(
        u, DINNER, wxp_t, nullptr, nullptr, nullptr, nullptr, nullptr, 128, DINNER, 0, DINNER / 8, psum);
    combine_xdbl<<<dim3(M * 96 / 256), blk, 0, stream>>>(psum, xdbl);

    // 7. delta = softplus(xdbl[:, :64] @ w_dt + b_dt)
    gemm128<<<dim3(M / 128, DINNER / 128), blk, 0, stream>>>(
        xdbl, 96, wdt_t, bdt_f, nullptr, delta_b, nullptr, nullptr, DINNER, DTRANK, 1, DTRANK, nullptr);

    // 8. chunked selective scan (+fused ymod) -> yb
    scan_phase1<<<dim3(NCHUNK * BATCH * DINNER / 256), blk, 0, stream>>>(
        delta_b, u, xdbl, Alog_f, Hend, Sdt);
    scan_phase2<<<dim3(BATCH * DINNER * DSTATE / 256), blk, 0, stream>>>(
        Hend, Sdt, Alog_f);
    scan_phase3<<<dim3(NCHUNK * BATCH * DINNER / 256), blk, 0, stream>>>(
        delta_b, u, xdbl, Alog_f, Hend, Dp_f, xr, yb);

    // 10. out = yb @ w_out + x1  (dtype per flag)
    gemm128<<<dim3(M / 128, NDIM / 128), blk, 0, stream>>>(
        yb, DINNER, wout_t, nullptr, x1b, (ushort*)d_out, (float*)d_out, flag, NDIM, DINNER, 0, DINNER, nullptr);
}

// Round 10
// 538.864 us; speedup vs baseline: 1.1572x; 1.1572x over previous
//
#include <hip/hip_runtime.h>

#define L_SEQ   2048
#define BATCH   2
#define NDIM    1024
#define NHEADS  16
#define HD      64
#define DSTATE  16
#define DCONV   4
#define DINNER  2048
#define DTRANK  64
#define CHUNK   32
#define NCHUNK  (L_SEQ / CHUNK)   // 64
#define SPLIT_KT 8                // KV tiles per attention split

typedef short  short8  __attribute__((ext_vector_type(8)));
typedef float  floatx4 __attribute__((ext_vector_type(4)));

#define AS1 __attribute__((address_space(1)))
#define AS3 __attribute__((address_space(3)))

__device__ __forceinline__ float bf2f(ushort u) {
    union { uint i; float f; } v; v.i = ((uint)u) << 16; return v.f;
}
__device__ __forceinline__ ushort f2bf(float f) {
    uint x = __float_as_uint(f);
    uint r = (x + 0x7fffu + ((x >> 16) & 1u)) >> 16;
    return (ushort)r;
}
__device__ __forceinline__ float silu_f(float x) {
    return x / (1.f + __expf(-x));
}
__device__ __forceinline__ void gld_lds16(const void* g, void* l) {
    __builtin_amdgcn_global_load_lds((const AS1 uint*)g, (AS3 uint*)l, 16, 0, 0);
}

// ---------------------------------------------------------------------------
// dtype probe: flag=1 -> input arrays are float32 (bit-pattern heuristic).
// ---------------------------------------------------------------------------
__global__ void probe_kernel(const ushort* __restrict__ x, int* __restrict__ flag) {
    __shared__ int cnt;
    if (threadIdx.x == 0) cnt = 0;
    __syncthreads();
    ushort w = x[threadIdx.x];
    int e = (w >> 7) & 0xff;
    if (w != 0 && (e < 100 || e > 140)) atomicAdd(&cnt, 1);
    __syncthreads();
    if (threadIdx.x == 0) *flag = (cnt >= 16) ? 1 : 0;
}

// ---------------------------------------------------------------------------
// dtype-agnostic convert: src is f32 if *flag else bf16 bits.
// ---------------------------------------------------------------------------
__global__ __launch_bounds__(256) void cvt_kernel(
    const void* __restrict__ src, ushort* __restrict__ db,
    float* __restrict__ df, int n, const int* __restrict__ flag)
{
    int i = blockIdx.x * 256 + threadIdx.x;
    if (i >= n) return;
    float v = (*flag) ? ((const float*)src)[i] : bf2f(((const ushort*)src)[i]);
    if (db) db[i] = f2bf(v);
    if (df) df[i] = v;
}

// ---------------------------------------------------------------------------
// one-launch conversion of all small parameter arrays -> f32.
// ---------------------------------------------------------------------------
__device__ __forceinline__ float cvt_one(const void* s, int i, int f) {
    return f ? ((const float*)s)[i] : bf2f(((const ushort*)s)[i]);
}
__global__ __launch_bounds__(256) void cvt_small(
    const void* bqkv, const void* bao, const void* convw, const void* convb,
    const void* bdt, const void* Alog, const void* Dp,
    float* __restrict__ bqkv_f, float* __restrict__ bao_f,
    float* __restrict__ convw_f, float* __restrict__ convb_f,
    float* __restrict__ bdt_f, float* __restrict__ Alog_f,
    float* __restrict__ Dp_f, const int* __restrict__ flag)
{
    int i = blockIdx.x * 256 + threadIdx.x;
    const int f = *flag;
    if      (i < 1152)   bqkv_f[i]          = cvt_one(bqkv,  i,          f);
    else if (i < 2176)   bao_f[i - 1152]    = cvt_one(bao,   i - 1152,   f);
    else if (i < 10368)  convw_f[i - 2176]  = cvt_one(convw, i - 2176,   f);
    else if (i < 12416)  convb_f[i - 10368] = cvt_one(convb, i - 10368,  f);
    else if (i < 14464)  bdt_f[i - 12416]   = cvt_one(bdt,   i - 12416,  f);
    else if (i < 47232)  Alog_f[i - 14464]  = cvt_one(Alog,  i - 14464,  f);
    else if (i < 49280)  Dp_f[i - 47232]    = cvt_one(Dp,    i - 47232,  f);
}

// ---------------------------------------------------------------------------
// convert + transpose: src (K,N) -> dst (N,K) bf16. K,N multiples of 32.
// ---------------------------------------------------------------------------
__global__ __launch_bounds__(256) void cvt_t_kernel(
    const void* __restrict__ src, ushort* __restrict__ dst,
    int K, int N, const int* __restrict__ flag)
{
    __shared__ float tile[32][33];
    const int tx = threadIdx.x & 31, ty = threadIdx.x >> 5;
    const int n0 = blockIdx.x * 32, k0 = blockIdx.y * 32;
    const int f = *flag;
    #pragma unroll
    for (int r = 0; r < 4; ++r) {
        int k = k0 + ty + r * 8;
        size_t o = (size_t)k * N + n0 + tx;
        tile[ty + r * 8][tx] = f ? ((const float*)src)[o] : bf2f(((const ushort*)src)[o]);
    }
    __syncthreads();
    #pragma unroll
    for (int r = 0; r < 4; ++r) {
        int n = n0 + ty + r * 8;
        dst[(size_t)n * K + k0 + tx] = f2bf(tile[tx][ty + r * 8]);
    }
}

// ---------------------------------------------------------------------------
// MFMA GEMM: 128x128 tile, BK=64, XOR k-slot swizzle.
// swap=0: m from blockIdx.y (round-8 order — best for skinny-K GEMMs).
// swap=1: m from blockIdx.x (XCD-locality: all n-blocks of an m-strip share
//         linear-id mod 8 -> same XCD L2 caches the A-strip; use for fat-K
//         GEMMs with large re-fetched A — w_in, w_out) [R9: delta 2x regress
//         with swap=1; w_out FETCH 72->2 MB with it. Per-call choice.]
// ---------------------------------------------------------------------------
__global__ __launch_bounds__(256) void gemm128(
    const ushort* __restrict__ A, int lda,
    const ushort* __restrict__ Wt,
    const float* __restrict__ bias,
    const ushort* __restrict__ resb,
    ushort* __restrict__ outb, float* __restrict__ outf,
    const int* __restrict__ dtflag,
    int N, int K, int act, int klen, float* __restrict__ psum, int swap)
{
    __shared__ __align__(16) ushort As[128 * 64];
    __shared__ __align__(16) ushort Bs[128 * 64];

    const int tid  = threadIdx.x;
    const int wave = tid >> 6;
    const int lane = tid & 63;
    const int wm = (wave >> 1) * 64;
    const int wn = (wave & 1) * 64;
    const int fm = lane & 15;
    const int quad = lane >> 4;
    const int m0 = (swap ? blockIdx.x : blockIdx.y) * 128;
    const int n0 = (swap ? blockIdx.y : blockIdx.x) * 128;

    floatx4 acc[4][4];
    #pragma unroll
    for (int i = 0; i < 4; ++i)
        #pragma unroll
        for (int j = 0; j < 4; ++j) acc[i][j] = (floatx4){0.f, 0.f, 0.f, 0.f};

    int rowv[4], kgv[4];
    #pragma unroll
    for (int j = 0; j < 4; ++j) {
        int c = wave * 256 + j * 64 + lane;
        rowv[j] = c >> 3;
        kgv[j]  = (((c & 7) ^ ((c >> 3) & 7))) * 8;
    }

    const int kbeg = psum ? (blockIdx.z * klen) : 0;
    const int kend = kbeg + klen;

    for (int k0 = kbeg; k0 < kend; k0 += 64) {
        #pragma unroll
        for (int j = 0; j < 4; ++j)
            gld_lds16(A  + (size_t)(m0 + rowv[j]) * lda + k0 + kgv[j],
                      &As[(wave * 256 + j * 64) * 8]);
        #pragma unroll
        for (int j = 0; j < 4; ++j)
            gld_lds16(Wt + (size_t)(n0 + rowv[j]) * K   + k0 + kgv[j],
                      &Bs[(wave * 256 + j * 64) * 8]);
        __syncthreads();

        #pragma unroll
        for (int h = 0; h < 2; ++h) {
            short8 af[4], bf[4];
            #pragma unroll
            for (int i = 0; i < 4; ++i) {
                int row = wm + i * 16 + fm;
                int slot = (h * 4 + quad) ^ (row & 7);
                af[i] = *(const short8*)&As[row * 64 + slot * 8];
            }
            #pragma unroll
            for (int j = 0; j < 4; ++j) {
                int row = wn + j * 16 + fm;
                int slot = (h * 4 + quad) ^ (row & 7);
                bf[j] = *(const short8*)&Bs[row * 64 + slot * 8];
            }
            #pragma unroll
            for (int i = 0; i < 4; ++i)
                #pragma unroll
                for (int j = 0; j < 4; ++j)
                    acc[i][j] = __builtin_amdgcn_mfma_f32_16x16x32_bf16(af[i], bf[j], acc[i][j], 0, 0, 0);
        }
        __syncthreads();
    }

    if (psum) {
        int mgrid = swap ? gridDim.x : gridDim.y;
        float* po = psum + (size_t)blockIdx.z * ((size_t)mgrid * 128) * N;
        #pragma unroll
        for (int j = 0; j < 4; ++j) {
            int col = n0 + wn + j * 16 + fm;
            #pragma unroll
            for (int i = 0; i < 4; ++i) {
                int rowb = m0 + wm + i * 16 + quad * 4;
                #pragma unroll
                for (int r = 0; r < 4; ++r)
                    po[(size_t)(rowb + r) * N + col] = acc[i][j][r];
            }
        }
        return;
    }

    const int flagv = dtflag ? *dtflag : 0;
    #pragma unroll
    for (int j = 0; j < 4; ++j) {
        int col = n0 + wn + j * 16 + fm;
        float bvv = bias ? bias[col] : 0.f;
        #pragma unroll
        for (int i = 0; i < 4; ++i) {
            int rowb = m0 + wm + i * 16 + quad * 4;
            #pragma unroll
            for (int r = 0; r < 4; ++r) {
                float v = acc[i][j][r] + bvv;
                if (act == 1)  // softplus via hw exp/log (log1pf libm is slow)
                    v = fmaxf(v, 0.f) + __logf(1.f + __expf(-fabsf(v)));
                size_t o = (size_t)(rowb + r) * N + col;
                if (resb) v += bf2f(resb[o]);
                if (dtflag) {
                    if (flagv) outf[o] = v; else outb[o] = f2bf(v);
                } else {
                    if (outb) outb[o] = f2bf(v);
                    if (outf) outf[o] = v;
                }
            }
        }
    }
}

// ---------------------------------------------------------------------------
// combine split-K partials (4096 x 128 padded) -> xdbl bf16 (stride 96).
// ---------------------------------------------------------------------------
__global__ __launch_bounds__(256) void combine_xdbl(
    const float* __restrict__ psum, ushort* __restrict__ xdbl)
{
    int idx = blockIdx.x * 256 + threadIdx.x;
    int row = idx / 96, col = idx - row * 96;
    float s = 0.f;
    #pragma unroll
    for (int z = 0; z < 8; ++z)
        s += psum[(size_t)z * 4096 * 128 + row * 128 + col];
    xdbl[idx] = f2bf(s);
}

// ---------------------------------------------------------------------------
// Flash MQA attention, split-KV, static-max softmax.
// ---------------------------------------------------------------------------
__global__ __launch_bounds__(256) void flash_attn_split(
    const ushort* __restrict__ qkv, ushort* __restrict__ att,
    ushort* __restrict__ partO, float* __restrict__ partL)
{
    __shared__ __align__(16) ushort Ks[64 * 72];
    __shared__ __align__(16) ushort Vt[64 * 72];
    __shared__ __align__(16) ushort Ps[4][32 * 72];

    const int tile = blockIdx.x;
    const int hg   = blockIdx.y;
    const int zz   = blockIdx.z;
    const int b = zz >> 2, s = zz & 3;
    const int q0 = tile * 32;
    const int nkv = (q0 >> 6) + 1;
    const int nsplit = (nkv + SPLIT_KT - 1) / SPLIT_KT;
    if (s >= nsplit) return;
    const int kt0 = s * SPLIT_KT;
    const int kt1 = (nkv < kt0 + SPLIT_KT) ? nkv : (kt0 + SPLIT_KT);

    const int tid  = threadIdx.x;
    const int wave = tid >> 6;
    const int lane = tid & 63;
    const int fm   = lane & 15;
    const int quad = lane >> 4;
    const int h    = hg * 4 + wave;

    const int srow = tid >> 3;
    const int scol = (tid & 7) * 8;
    const int vsw  = (tid & 7) << 3;

    short8 qf[2][2];
    #pragma unroll
    for (int i = 0; i < 2; ++i)
        #pragma unroll
        for (int kh = 0; kh < 2; ++kh)
            qf[i][kh] = *(const short8*)(qkv +
                (size_t)(b * L_SEQ + q0 + i * 16 + fm) * 1152 + h * HD + kh * 32 + quad * 8);

    floatx4 acc[2][4];
    float l_part[2][4];
    #pragma unroll
    for (int i = 0; i < 2; ++i) {
        #pragma unroll
        for (int j = 0; j < 4; ++j) acc[i][j] = (floatx4){0.f, 0.f, 0.f, 0.f};
        #pragma unroll
        for (int r = 0; r < 4; ++r) l_part[i][r] = 0.f;
    }

    for (int kt = kt0; kt < kt1; ++kt) {
        const int kv0 = kt * 64;
        __syncthreads();
        #pragma unroll
        for (int pass = 0; pass < 2; ++pass) {
            int row = srow + pass * 32;
            const ushort* kp = qkv + (size_t)(b * L_SEQ + kv0 + row) * 1152 + NDIM + scol;
            *(short8*)&Ks[row * 72 + scol] = *(const short8*)kp;
            short8 t = *(const short8*)(kp + HD);
            int mw = row ^ vsw;
            #pragma unroll
            for (int i2 = 0; i2 < 8; ++i2) Vt[(scol + i2) * 72 + mw] = (ushort)t[i2];
        }
        __syncthreads();

        floatx4 sp[2][4];
        #pragma unroll
        for (int j = 0; j < 4; ++j) {
            short8 kf0 = *(const short8*)&Ks[(j * 16 + fm) * 72 + quad * 8];
            short8 kf1 = *(const short8*)&Ks[(j * 16 + fm) * 72 + 32 + quad * 8];
            #pragma unroll
            for (int i = 0; i < 2; ++i) {
                floatx4 z = (floatx4){0.f, 0.f, 0.f, 0.f};
                z = __builtin_amdgcn_mfma_f32_16x16x32_bf16(qf[i][0], kf0, z, 0, 0, 0);
                z = __builtin_amdgcn_mfma_f32_16x16x32_bf16(qf[i][1], kf1, z, 0, 0, 0);
                sp[i][j] = z;
            }
        }

        const bool diag = (kt == nkv - 1);
        #pragma unroll
        for (int i = 0; i < 2; ++i)
            #pragma unroll
            for (int j = 0; j < 4; ++j) {
                int col = kv0 + j * 16 + fm;
                #pragma unroll
                for (int r = 0; r < 4; ++r) {
                    float p = __expf(sp[i][j][r] * 0.125f);
                    if (diag) {
                        int rowg = q0 + i * 16 + quad * 4 + r;
                        if (col > rowg) p = 0.f;
                    }
                    sp[i][j][r] = p;
                    l_part[i][r] += p;
                }
            }

        #pragma unroll
        for (int i = 0; i < 2; ++i)
            #pragma unroll
            for (int j = 0; j < 4; ++j)
                #pragma unroll
                for (int r = 0; r < 4; ++r)
                    Ps[wave][(i * 16 + quad * 4 + r) * 72 + j * 16 + fm] = f2bf(sp[i][j][r]);

        short8 pf[2][2];
        #pragma unroll
        for (int i = 0; i < 2; ++i) {
            pf[i][0] = *(const short8*)&Ps[wave][(i * 16 + fm) * 72 + quad * 8];
            pf[i][1] = *(const short8*)&Ps[wave][(i * 16 + fm) * 72 + 32 + quad * 8];
        }

        #pragma unroll
        for (int dj = 0; dj < 4; ++dj) {
            int d = dj * 16 + fm;
            int sw8 = ((d >> 3) & 7) << 3;
            short8 vf0 = *(const short8*)&Vt[d * 72 + ((quad * 8) ^ sw8)];
            short8 vf1 = *(const short8*)&Vt[d * 72 + ((32 + quad * 8) ^ sw8)];
            #pragma unroll
            for (int i = 0; i < 2; ++i) {
                acc[i][dj] = __builtin_amdgcn_mfma_f32_16x16x32_bf16(pf[i][0], vf0, acc[i][dj], 0, 0, 0);
                acc[i][dj] = __builtin_amdgcn_mfma_f32_16x16x32_bf16(pf[i][1], vf1, acc[i][dj], 0, 0, 0);
            }
        }
    }

    float l_red[2][4];
    #pragma unroll
    for (int i = 0; i < 2; ++i)
        #pragma unroll
        for (int r = 0; r < 4; ++r) {
            float rs = l_part[i][r];
            rs += __shfl_xor(rs, 1, 16);
            rs += __shfl_xor(rs, 2, 16);
            rs += __shfl_xor(rs, 4, 16);
            rs += __shfl_xor(rs, 8, 16);
            l_red[i][r] = rs;
        }

    if (nsplit == 1) {
        #pragma unroll
        for (int i = 0; i < 2; ++i) {
            float inv[4];
            #pragma unroll
            for (int r = 0; r < 4; ++r) inv[r] = 1.f / l_red[i][r];
            #pragma unroll
            for (int dj = 0; dj < 4; ++dj)
                #pragma unroll
                for (int r = 0; r < 4; ++r) {
                    int q = q0 + i * 16 + quad * 4 + r;
                    att[(size_t)(b * L_SEQ + q) * NDIM + h * HD + dj * 16 + fm] =
                        f2bf(acc[i][dj][r] * inv[r]);
                }
        }
    } else {
        size_t pbase = ((size_t)((s * 2 + b) * 16 + h)) * L_SEQ;
        #pragma unroll
        for (int i = 0; i < 2; ++i)
            #pragma unroll
            for (int dj = 0; dj < 4; ++dj)
                #pragma unroll
                for (int r = 0; r < 4; ++r) {
                    int q = q0 + i * 16 + quad * 4 + r;
                    partO[(pbase + q) * 64 + dj * 16 + fm] = f2bf(acc[i][dj][r]);
                }
        if (fm == 0) {
            #pragma unroll
            for (int i = 0; i < 2; ++i)
                #pragma unroll
                for (int r = 0; r < 4; ++r)
                    partL[pbase + q0 + i * 16 + quad * 4 + r] = l_red[i][r];
        }
    }
}

// ---------------------------------------------------------------------------
// combine attention split partials for q >= 512.
// ---------------------------------------------------------------------------
__global__ __launch_bounds__(256) void attn_combine(
    const ushort* __restrict__ partO, const float* __restrict__ partL,
    ushort* __restrict__ att)
{
    int gid = blockIdx.x * 256 + threadIdx.x;
    int t8 = gid & 7;
    int row = gid >> 3;
    int q  = 512 + (row % 1536);
    int bh = row / 1536;
    int b = bh >> 4, h = bh & 15;
    int nsplit = (((q >> 5) >> 1) + 1 + SPLIT_KT - 1) / SPLIT_KT;

    float sum[8] = {0.f, 0.f, 0.f, 0.f, 0.f, 0.f, 0.f, 0.f};
    float L = 0.f;
    for (int s = 0; s < nsplit; ++s) {
        size_t pbase = ((size_t)((s * 2 + b) * 16 + h)) * L_SEQ + q;
        L += partL[pbase];
        short8 o = *(const short8*)&partO[pbase * 64 + t8 * 8];
        #pragma unroll
        for (int k = 0; k < 8; ++k) sum[k] += bf2f((ushort)o[k]);
    }
    float inv = 1.f / L;
    short8 outv;
    #pragma unroll
    for (int k = 0; k < 8; ++k) outv[k] = (short)f2bf(sum[k] * inv);
    *(short8*)&att[((size_t)(b * L_SEQ + q)) * NDIM + h * HD + t8 * 8] = outv;
}

// ---------------------------------------------------------------------------
// depthwise conv (window 4, left pad 3) + bias + silu.
// ---------------------------------------------------------------------------
__global__ __launch_bounds__(256) void conv_silu(
    const ushort* __restrict__ xr, const float* __restrict__ conv_w,
    const float* __restrict__ conv_b, ushort* __restrict__ u)
{
    const int idx = blockIdx.x * 256 + threadIdx.x;
    const int c  = idx & (DINNER - 1);
    const int bl = idx >> 11;
    const int l  = bl & (L_SEQ - 1);

    float acc = conv_b[c];
    #pragma unroll
    for (int j = 0; j < DCONV; ++j) {
        int ls = l - 3 + j;
        if (ls >= 0)
            acc += bf2f(xr[(size_t)(bl - 3 + j) * (2 * DINNER) + c]) * conv_w[c * DCONV + j];
    }
    u[idx] = f2bf(silu_f(acc));
}

// ---------------------------------------------------------------------------
// Chunked selective scan, phase 1.
// ---------------------------------------------------------------------------
__global__ __launch_bounds__(256) void scan_phase1(
    const ushort* __restrict__ delta, const ushort* __restrict__ u,
    const ushort* __restrict__ xdbl, const float* __restrict__ A_log,
    float* __restrict__ Hend, float* __restrict__ Sdt)
{
    const int idx = blockIdx.x * 256 + threadIdx.x;
    const int d = idx & (DINNER - 1);
    const int b = (idx >> 11) & (BATCH - 1);
    const int c = idx >> 12;

    float Av[DSTATE], h[DSTATE];
    #pragma unroll
    for (int n = 0; n < DSTATE; ++n) {
        Av[n] = -__expf(A_log[d * DSTATE + n]);
        h[n] = 0.f;
    }

    const int t0 = c * CHUNK;
    size_t bd = ((size_t)b * L_SEQ + t0) * DINNER + d;
    size_t bx = ((size_t)b * L_SEQ + t0) * 96 + DTRANK;
    float sdt = 0.f;

    for (int t = 0; t < CHUNK; ++t) {
        float dt = bf2f(delta[bd]);
        float uv = bf2f(u[bd]);
        sdt += dt;
        float du = dt * uv;
        short8 B0 = *(const short8*)&xdbl[bx];
        short8 B1 = *(const short8*)&xdbl[bx + 8];
        #pragma unroll
        for (int n = 0; n < 8; ++n)
            h[n] = __expf(dt * Av[n]) * h[n] + du * bf2f((ushort)B0[n]);
        #pragma unroll
        for (int n = 0; n < 8; ++n)
            h[8 + n] = __expf(dt * Av[8 + n]) * h[8 + n] + du * bf2f((ushort)B1[n]);
        bd += DINNER; bx += 96;
    }

    size_t ho = (((size_t)c * BATCH + b) * DINNER + d) * DSTATE;
    #pragma unroll
    for (int n = 0; n < DSTATE; n += 4)
        *(floatx4*)&Hend[ho + n] = (floatx4){h[n], h[n + 1], h[n + 2], h[n + 3]};
    Sdt[((size_t)c * BATCH + b) * DINNER + d] = sdt;
}

// ---------------------------------------------------------------------------
// phase 2: in-place exclusive combine over 64 chunks.
// ---------------------------------------------------------------------------
__global__ __launch_bounds__(256) void scan_phase2(
    float* __restrict__ H, const float* __restrict__ Sdt,
    const float* __restrict__ A_log)
{
    const int idx = blockIdx.x * 256 + threadIdx.x;
    const int n = idx & (DSTATE - 1);
    const int d = (idx >> 4) & (DINNER - 1);
    const int b = idx >> 15;

    const float Av = -__expf(A_log[d * DSTATE + n]);
    float hin = 0.f;
    for (int c = 0; c < NCHUNK; ++c) {
        size_t o  = (((size_t)c * BATCH + b) * DINNER + d) * DSTATE + n;
        float e   = H[o];
        float dAc = __expf(Av * Sdt[((size_t)c * BATCH + b) * DINNER + d]);
        H[o] = hin;
        hin = dAc * hin + e;
    }
}

// ---------------------------------------------------------------------------
// phase 3: redo chunk scan from Hin, emit y, fused ymod.
// ---------------------------------------------------------------------------
__global__ __launch_bounds__(256) void scan_phase3(
    const ushort* __restrict__ delta, const ushort* __restrict__ u,
    const ushort* __restrict__ xdbl, const float* __restrict__ A_log,
    const float* __restrict__ Hin, const float* __restrict__ Dp,
    const ushort* __restrict__ xr, ushort* __restrict__ yb)
{
    const int idx = blockIdx.x * 256 + threadIdx.x;
    const int d = idx & (DINNER - 1);
    const int b = (idx >> 11) & (BATCH - 1);
    const int c = idx >> 12;

    float Av[DSTATE], h[DSTATE];
    size_t ho = (((size_t)c * BATCH + b) * DINNER + d) * DSTATE;
    #pragma unroll
    for (int n = 0; n < DSTATE; n += 4) {
        floatx4 hv = *(const floatx4*)&Hin[ho + n];
        h[n] = hv[0]; h[n + 1] = hv[1]; h[n + 2] = hv[2]; h[n + 3] = hv[3];
    }
    #pragma unroll
    for (int n = 0; n < DSTATE; ++n)
        Av[n] = -__expf(A_log[d * DSTATE + n]);

    const float Dpd = Dp[d];
    const int t0 = c * CHUNK;
    size_t bd = ((size_t)b * L_SEQ + t0) * DINNER + d;
    size_t bx = ((size_t)b * L_SEQ + t0) * 96 + DTRANK;
    size_t br = ((size_t)b * L_SEQ + t0) * (2 * DINNER) + DINNER + d;

    for (int t = 0; t < CHUNK; ++t) {
        float dt = bf2f(delta[bd]);
        float uv = bf2f(u[bd]);
        float du = dt * uv;
        short8 B0 = *(const short8*)&xdbl[bx];
        short8 B1 = *(const short8*)&xdbl[bx + 8];
        short8 C0 = *(const short8*)&xdbl[bx + 16];
        short8 C1 = *(const short8*)&xdbl[bx + 24];
        float y = 0.f;
        #pragma unroll
        for (int n = 0; n < 8; ++n) {
            h[n] = __expf(dt * Av[n]) * h[n] + du * bf2f((ushort)B0[n]);
            y += h[n] * bf2f((ushort)C0[n]);
        }
        #pragma unroll
        for (int n = 0; n < 8; ++n) {
            h[8 + n] = __expf(dt * Av[8 + n]) * h[8 + n] + du * bf2f((ushort)B1[n]);
            y += h[8 + n] * bf2f((ushort)C1[n]);
        }
        float yv = y + uv * Dpd;
        float r  = bf2f(xr[br]);
        yb[bd] = f2bf(yv * silu_f(r));
        bd += DINNER; bx += 96; br += 2 * DINNER;
    }
}

// ---------------------------------------------------------------------------
extern "C" void kernel_launch(void* const* d_in, const int* in_sizes, int n_in,
                              void* d_out, int out_size, void* d_ws, size_t ws_size,
                              hipStream_t stream) {
    const void* x_raw      = d_in[0];
    const void* wqkv_raw   = d_in[1];
    const void* bqkv_raw   = d_in[2];
    const void* wao_raw    = d_in[3];
    const void* bao_raw    = d_in[4];
    const void* win_raw    = d_in[5];
    const void* convw_raw  = d_in[6];
    const void* convb_raw  = d_in[7];
    const void* wxp_raw    = d_in[8];
    const void* wdt_raw    = d_in[9];
    const void* bdt_raw    = d_in[10];
    const void* Alog_raw   = d_in[11];
    const void* Dp_raw     = d_in[12];
    const void* wout_raw   = d_in[13];

    const int M = BATCH * L_SEQ;  // 4096

    char* p = (char*)d_ws;
    size_t off = 0;
    auto A_ = [&](size_t bytes) { void* q = p + off; off += (bytes + 255) & ~255ull; return q; };

    ushort* x_b    = (ushort*)A_((size_t)M * NDIM * 2);
    ushort* wqkv_t = (ushort*)A_((size_t)NDIM * 1152 * 2);
    ushort* wao_t  = (ushort*)A_((size_t)NDIM * NDIM * 2);
    ushort* win_t  = (ushort*)A_((size_t)NDIM * 4096 * 2);
    float*  psum   = (float*)x_b;
    ushort* yb     = x_b;
    float*  Sdt    = (float*)(x_b + (size_t)M * DINNER);

    ushort* qkv    = (ushort*)A_((size_t)M * 1152 * 2);
    ushort* att    = (ushort*)A_((size_t)M * NDIM * 2);
    float*  Hend   = (float*)qkv;

    ushort* delta_b = (ushort*)A_((size_t)M * DINNER * 2);

    ushort* wxp_t  = (ushort*)A_((size_t)128 * DINNER * 2);
    ushort* wdt_t  = (ushort*)A_((size_t)DTRANK * DINNER * 2);
    ushort* wout_t = (ushort*)A_((size_t)DINNER * NDIM * 2);
    float*  bqkv_f = (float*)A_(1152 * 4);
    float*  bao_f  = (float*)A_(NDIM * 4);
    float*  convw_f= (float*)A_((size_t)DINNER * DCONV * 4);
    float*  convb_f= (float*)A_(DINNER * 4);
    float*  bdt_f  = (float*)A_(DINNER * 4);
    float*  Alog_f = (float*)A_((size_t)DINNER * DSTATE * 4);
    float*  Dp_f   = (float*)A_(DINNER * 4);
    int*    flag   = (int*)A_(256);
    ushort* x1b    = (ushort*)A_((size_t)M * NDIM * 2);
    ushort* xr     = (ushort*)A_((size_t)M * 4096 * 2);
    ushort* u      = (ushort*)A_((size_t)M * DINNER * 2);
    ushort* xdbl   = (ushort*)A_((size_t)M * 96 * 2);

    ushort* partO = xr;
    float*  partL = (float*)u;

    dim3 blk(256);
    auto cvt_t = [&](const void* src, ushort* dst, int K, int N) {
        cvt_t_kernel<<<dim3(N / 32, K / 32), blk, 0, stream>>>(src, dst, K, N, flag);
    };

    // 0. dtype probe + canonicalize (+ transpose weights)
    probe_kernel<<<dim3(1), blk, 0, stream>>>((const ushort*)x_raw, flag);
    cvt_kernel<<<dim3(M * NDIM / 256), blk, 0, stream>>>(x_raw, x_b, nullptr, M * NDIM, flag);
    cvt_t(wqkv_raw, wqkv_t, NDIM, 1152);
    cvt_t(wao_raw,  wao_t,  NDIM, NDIM);
    cvt_t(win_raw,  win_t,  NDIM, 4096);
    cvt_t(wxp_raw,  wxp_t,  DINNER, 96);
    hipMemsetAsync(wxp_t + (size_t)96 * DINNER, 0, (size_t)32 * DINNER * 2, stream);
    cvt_t(wdt_raw,  wdt_t,  DTRANK, DINNER);
    cvt_t(wout_raw, wout_t, DINNER, NDIM);
    cvt_small<<<dim3((49280 + 255) / 256), blk, 0, stream>>>(
        bqkv_raw, bao_raw, convw_raw, convb_raw, bdt_raw, Alog_raw, Dp_raw,
        bqkv_f, bao_f, convw_f, convb_f, bdt_f, Alog_f, Dp_f, flag);

    // 1. qkv = x @ wqkv + bqkv   (swap=0: skinny-N, round-8 order)
    gemm128<<<dim3(1152 / 128, M / 128), blk, 0, stream>>>(
        x_b, NDIM, wqkv_t, bqkv_f, nullptr, qkv, nullptr, nullptr, 1152, NDIM, 0, NDIM, nullptr, 0);

    // 2. flash attention (split-KV) + combine
    flash_attn_split<<<dim3(L_SEQ / 32, NHEADS / 4, BATCH * 4), blk, 0, stream>>>(
        qkv, att, partO, partL);
    attn_combine<<<dim3(1536), blk, 0, stream>>>(partO, partL, att);

    // 3. x1 = att @ w_ao + b_ao + x   (swap=0)
    gemm128<<<dim3(NDIM / 128, M / 128), blk, 0, stream>>>(
        att, NDIM, wao_t, bao_f, x_b, x1b, nullptr, nullptr, NDIM, NDIM, 0, NDIM, nullptr, 0);

    // 4. xr = x1 @ w_in   (swap=1: XCD-local A-strip; R8 FETCH evidence)
    gemm128<<<dim3(M / 128, 4096 / 128), blk, 0, stream>>>(
        x1b, NDIM, win_t, nullptr, nullptr, xr, nullptr, nullptr, 4096, NDIM, 0, NDIM, nullptr, 1);

    // 5. conv + silu -> u
    conv_silu<<<dim3(M * DINNER / 256), blk, 0, stream>>>(xr, convw_f, convb_f, u);

    // 6. xdbl = u @ w_xproj  (split-K=8, swap=0, round-8 grid)
    gemm128<<<dim3(1, M / 128, 8), blk, 0, stream>>>(
        u, DINNER, wxp_t, nullptr, nullptr, nullptr, nullptr, nullptr, 128, DINNER, 0, DINNER / 8, psum, 0);
    combine_xdbl<<<dim3(M * 96 / 256), blk, 0, stream>>>(psum, xdbl);

    // 7. delta = softplus(xdbl[:, :64] @ w_dt + b_dt)  (swap=0 — R9 regress fix)
    gemm128<<<dim3(DINNER / 128, M / 128), blk, 0, stream>>>(
        xdbl, 96, wdt_t, bdt_f, nullptr, delta_b, nullptr, nullptr, DINNER, DTRANK, 1, DTRANK, nullptr, 0);

    // 8. chunked selective scan (+fused ymod) -> yb
    scan_phase1<<<dim3(NCHUNK * BATCH * DINNER / 256), blk, 0, stream>>>(
        delta_b, u, xdbl, Alog_f, Hend, Sdt);
    scan_phase2<<<dim3(BATCH * DINNER * DSTATE / 256), blk, 0, stream>>>(
        Hend, Sdt, Alog_f);
    scan_phase3<<<dim3(NCHUNK * BATCH * DINNER / 256), blk, 0, stream>>>(
        delta_b, u, xdbl, Alog_f, Hend, Dp_f, xr, yb);

    // 10. out = yb @ w_out + x1  (swap=1: XCD-local A-strip; R8→R9 FETCH 72->2 MB)
    gemm128<<<dim3(M / 128, NDIM / 128), blk, 0, stream>>>(
        yb, DINNER, wout_t, nullptr, x1b, (ushort*)d_out, (float*)d_out, flag, NDIM, DINNER, 0, DINNER, nullptr, 1);
}

// Round 11
// 538.320 us; speedup vs baseline: 1.1584x; 1.0010x over previous
//
#include <hip/hip_runtime.h>

#define L_SEQ   2048
#define BATCH   2
#define NDIM    1024
#define NHEADS  16
#define HD      64
#define DSTATE  16
#define DCONV   4
#define DINNER  2048
#define DTRANK  64
#define CHUNK   32
#define NCHUNK  (L_SEQ / CHUNK)   // 64
#define SPLIT_KT 8                // KV tiles per attention split

typedef short  short8  __attribute__((ext_vector_type(8)));
typedef float  floatx4 __attribute__((ext_vector_type(4)));

#define AS1 __attribute__((address_space(1)))
#define AS3 __attribute__((address_space(3)))

__device__ __forceinline__ float bf2f(ushort u) {
    union { uint i; float f; } v; v.i = ((uint)u) << 16; return v.f;
}
__device__ __forceinline__ ushort f2bf(float f) {
    uint x = __float_as_uint(f);
    uint r = (x + 0x7fffu + ((x >> 16) & 1u)) >> 16;
    return (ushort)r;
}
__device__ __forceinline__ float silu_f(float x) {
    return x / (1.f + __expf(-x));
}
__device__ __forceinline__ void gld_lds16(const void* g, void* l) {
    __builtin_amdgcn_global_load_lds((const AS1 uint*)g, (AS3 uint*)l, 16, 0, 0);
}
__device__ __forceinline__ float cvt_one(const void* s, int i, int f) {
    return f ? ((const float*)s)[i] : bf2f(((const ushort*)s)[i]);
}

// ---------------------------------------------------------------------------
// MEGA PREP: one launch does dtype-probe (locally per block), x convert,
// all 6 weight transposes, wxp pad, and small-param f32 conversion.
// Block ranges:
//   [0,16384)        x convert (bf16 canonical)
//   +1152            wqkv^T  (1024,1152)->(1152,1024)
//   +1024            wao^T   (1024,1024)
//   +4096            win^T   (1024,4096)->(4096,1024)
//   +192             wxp^T   (2048,96)->(96,2048) rows of padded (128,2048)
//   +128             wdt^T   (64,2048)->(2048,64)
//   +2048            wout^T  (2048,1024)->(1024,2048)
//   +256             wxp pad rows 96..127 = 0
//   +193             small params -> f32
// ---------------------------------------------------------------------------
__global__ __launch_bounds__(256) void prep_kernel(
    const void* __restrict__ x_raw,
    const void* __restrict__ wqkv, const void* __restrict__ wao,
    const void* __restrict__ win,  const void* __restrict__ wxp,
    const void* __restrict__ wdt,  const void* __restrict__ wout,
    const void* __restrict__ bqkv, const void* __restrict__ bao,
    const void* __restrict__ convw, const void* __restrict__ convb,
    const void* __restrict__ bdt,  const void* __restrict__ Alog,
    const void* __restrict__ Dp,
    ushort* __restrict__ x_b, ushort* __restrict__ wqkv_t,
    ushort* __restrict__ wao_t, ushort* __restrict__ win_t,
    ushort* __restrict__ wxp_t, ushort* __restrict__ wdt_t,
    ushort* __restrict__ wout_t,
    float* __restrict__ bqkv_f, float* __restrict__ bao_f,
    float* __restrict__ convw_f, float* __restrict__ convb_f,
    float* __restrict__ bdt_f, float* __restrict__ Alog_f,
    float* __restrict__ Dp_f, int* __restrict__ flag)
{
    __shared__ int cnt;
    __shared__ float tile[32][33];
    if (threadIdx.x == 0) cnt = 0;
    __syncthreads();
    {
        ushort w = ((const ushort*)x_raw)[threadIdx.x];
        int e = (w >> 7) & 0xff;
        if (w != 0 && (e < 100 || e > 140)) atomicAdd(&cnt, 1);
    }
    __syncthreads();
    const int f = (cnt >= 16) ? 1 : 0;
    if (blockIdx.x == 0 && threadIdx.x == 0) *flag = f;

    int id = blockIdx.x;
    if (id < 16384) {                               // x convert
        int i = id * 256 + threadIdx.x;
        x_b[i] = f2bf(cvt_one(x_raw, i, f));
        return;
    }
    id -= 16384;

    const void* src = nullptr; ushort* dst = nullptr; int K = 0, N = 0;
    if (id < 1152)                     { src = wqkv; dst = wqkv_t; K = 1024; N = 1152; }
    else if ((id -= 1152) < 1024)      { src = wao;  dst = wao_t;  K = 1024; N = 1024; }
    else if ((id -= 1024) < 4096)      { src = win;  dst = win_t;  K = 1024; N = 4096; }
    else if ((id -= 4096) < 192)       { src = wxp;  dst = wxp_t;  K = 2048; N = 96;   }
    else if ((id -= 192)  < 128)       { src = wdt;  dst = wdt_t;  K = 64;   N = 2048; }
    else if ((id -= 128)  < 2048)      { src = wout; dst = wout_t; K = 2048; N = 1024; }
    else {
        id -= 2048;
        if (id < 256) {                              // wxp pad rows 96..127
            wxp_t[(size_t)96 * DINNER + id * 256 + threadIdx.x] = 0;
        } else {                                     // small params
            int i = (id - 256) * 256 + threadIdx.x;
            if      (i < 1152)   bqkv_f[i]          = cvt_one(bqkv,  i,          f);
            else if (i < 2176)   bao_f[i - 1152]    = cvt_one(bao,   i - 1152,   f);
            else if (i < 10368)  convw_f[i - 2176]  = cvt_one(convw, i - 2176,   f);
            else if (i < 12416)  convb_f[i - 10368] = cvt_one(convb, i - 10368,  f);
            else if (i < 14464)  bdt_f[i - 12416]   = cvt_one(bdt,   i - 12416,  f);
            else if (i < 47232)  Alog_f[i - 14464]  = cvt_one(Alog,  i - 14464,  f);
            else if (i < 49280)  Dp_f[i - 47232]    = cvt_one(Dp,    i - 47232,  f);
        }
        return;
    }

    // 32x32 transpose tile: src (K,N) -> dst (N,K)
    const int ntn = N / 32;
    const int n0 = (id % ntn) * 32, k0 = (id / ntn) * 32;
    const int tx = threadIdx.x & 31, ty = threadIdx.x >> 5;
    #pragma unroll
    for (int r = 0; r < 4; ++r) {
        size_t o = (size_t)(k0 + ty + r * 8) * N + n0 + tx;
        tile[ty + r * 8][tx] = cvt_one(src, (int)o, f);
    }
    __syncthreads();
    #pragma unroll
    for (int r = 0; r < 4; ++r) {
        int n = n0 + ty + r * 8;
        dst[(size_t)n * K + k0 + tx] = f2bf(tile[tx][ty + r * 8]);
    }
}

// ---------------------------------------------------------------------------
// MFMA GEMM: 128x128 tile, BK=64, XOR k-slot swizzle.
// swap=0: m from blockIdx.y (skinny-K GEMMs). swap=1: m from blockIdx.x
// (XCD-locality for fat-K w_in/w_out) [R9: per-call choice validated].
// ---------------------------------------------------------------------------
__global__ __launch_bounds__(256) void gemm128(
    const ushort* __restrict__ A, int lda,
    const ushort* __restrict__ Wt,
    const float* __restrict__ bias,
    const ushort* __restrict__ resb,
    ushort* __restrict__ outb, float* __restrict__ outf,
    const int* __restrict__ dtflag,
    int N, int K, int act, int klen, float* __restrict__ psum, int swap)
{
    __shared__ __align__(16) ushort As[128 * 64];
    __shared__ __align__(16) ushort Bs[128 * 64];

    const int tid  = threadIdx.x;
    const int wave = tid >> 6;
    const int lane = tid & 63;
    const int wm = (wave >> 1) * 64;
    const int wn = (wave & 1) * 64;
    const int fm = lane & 15;
    const int quad = lane >> 4;
    const int m0 = (swap ? blockIdx.x : blockIdx.y) * 128;
    const int n0 = (swap ? blockIdx.y : blockIdx.x) * 128;

    floatx4 acc[4][4];
    #pragma unroll
    for (int i = 0; i < 4; ++i)
        #pragma unroll
        for (int j = 0; j < 4; ++j) acc[i][j] = (floatx4){0.f, 0.f, 0.f, 0.f};

    int rowv[4], kgv[4];
    #pragma unroll
    for (int j = 0; j < 4; ++j) {
        int c = wave * 256 + j * 64 + lane;
        rowv[j] = c >> 3;
        kgv[j]  = (((c & 7) ^ ((c >> 3) & 7))) * 8;
    }

    const int kbeg = psum ? (blockIdx.z * klen) : 0;
    const int kend = kbeg + klen;

    for (int k0 = kbeg; k0 < kend; k0 += 64) {
        #pragma unroll
        for (int j = 0; j < 4; ++j)
            gld_lds16(A  + (size_t)(m0 + rowv[j]) * lda + k0 + kgv[j],
                      &As[(wave * 256 + j * 64) * 8]);
        #pragma unroll
        for (int j = 0; j < 4; ++j)
            gld_lds16(Wt + (size_t)(n0 + rowv[j]) * K   + k0 + kgv[j],
                      &Bs[(wave * 256 + j * 64) * 8]);
        __syncthreads();

        #pragma unroll
        for (int h = 0; h < 2; ++h) {
            short8 af[4], bf[4];
            #pragma unroll
            for (int i = 0; i < 4; ++i) {
                int row = wm + i * 16 + fm;
                int slot = (h * 4 + quad) ^ (row & 7);
                af[i] = *(const short8*)&As[row * 64 + slot * 8];
            }
            #pragma unroll
            for (int j = 0; j < 4; ++j) {
                int row = wn + j * 16 + fm;
                int slot = (h * 4 + quad) ^ (row & 7);
                bf[j] = *(const short8*)&Bs[row * 64 + slot * 8];
            }
            #pragma unroll
            for (int i = 0; i < 4; ++i)
                #pragma unroll
                for (int j = 0; j < 4; ++j)
                    acc[i][j] = __builtin_amdgcn_mfma_f32_16x16x32_bf16(af[i], bf[j], acc[i][j], 0, 0, 0);
        }
        __syncthreads();
    }

    if (psum) {
        int mgrid = swap ? gridDim.x : gridDim.y;
        float* po = psum + (size_t)blockIdx.z * ((size_t)mgrid * 128) * N;
        #pragma unroll
        for (int j = 0; j < 4; ++j) {
            int col = n0 + wn + j * 16 + fm;
            #pragma unroll
            for (int i = 0; i < 4; ++i) {
                int rowb = m0 + wm + i * 16 + quad * 4;
                #pragma unroll
                for (int r = 0; r < 4; ++r)
                    po[(size_t)(rowb + r) * N + col] = acc[i][j][r];
            }
        }
        return;
    }

    const int flagv = dtflag ? *dtflag : 0;
    #pragma unroll
    for (int j = 0; j < 4; ++j) {
        int col = n0 + wn + j * 16 + fm;
        float bvv = bias ? bias[col] : 0.f;
        #pragma unroll
        for (int i = 0; i < 4; ++i) {
            int rowb = m0 + wm + i * 16 + quad * 4;
            #pragma unroll
            for (int r = 0; r < 4; ++r) {
                float v = acc[i][j][r] + bvv;
                if (act == 1)
                    v = fmaxf(v, 0.f) + __logf(1.f + __expf(-fabsf(v)));
                size_t o = (size_t)(rowb + r) * N + col;
                if (resb) v += bf2f(resb[o]);
                if (dtflag) {
                    if (flagv) outf[o] = v; else outb[o] = f2bf(v);
                } else {
                    if (outb) outb[o] = f2bf(v);
                    if (outf) outf[o] = v;
                }
            }
        }
    }
}

// ---------------------------------------------------------------------------
// combine split-K partials (4096 x 128 padded) -> xdbl bf16 (stride 96).
// ---------------------------------------------------------------------------
__global__ __launch_bounds__(256) void combine_xdbl(
    const float* __restrict__ psum, ushort* __restrict__ xdbl)
{
    int idx = blockIdx.x * 256 + threadIdx.x;
    int row = idx / 96, col = idx - row * 96;
    float s = 0.f;
    #pragma unroll
    for (int z = 0; z < 8; ++z)
        s += psum[(size_t)z * 4096 * 128 + row * 128 + col];
    xdbl[idx] = f2bf(s);
}

// ---------------------------------------------------------------------------
// Flash MQA attention, split-KV, static-max softmax.
// K staged via global_load_lds with XOR chunk swizzle (stride 64, conflict-
// free frag reads — same pattern as gemm128). V^T scatter + Ps unchanged.
// ---------------------------------------------------------------------------
__global__ __launch_bounds__(256) void flash_attn_split(
    const ushort* __restrict__ qkv, ushort* __restrict__ att,
    ushort* __restrict__ partO, float* __restrict__ partL)
{
    __shared__ __align__(16) ushort Ks[64 * 64];
    __shared__ __align__(16) ushort Vt[64 * 72];
    __shared__ __align__(16) ushort Ps[4][32 * 72];

    const int tile = blockIdx.x;
    const int hg   = blockIdx.y;
    const int zz   = blockIdx.z;
    const int b = zz >> 2, s = zz & 3;
    const int q0 = tile * 32;
    const int nkv = (q0 >> 6) + 1;
    const int nsplit = (nkv + SPLIT_KT - 1) / SPLIT_KT;
    if (s >= nsplit) return;
    const int kt0 = s * SPLIT_KT;
    const int kt1 = (nkv < kt0 + SPLIT_KT) ? nkv : (kt0 + SPLIT_KT);

    const int tid  = threadIdx.x;
    const int wave = tid >> 6;
    const int lane = tid & 63;
    const int fm   = lane & 15;
    const int quad = lane >> 4;
    const int h    = hg * 4 + wave;

    const int srow = tid >> 3;
    const int scol = (tid & 7) * 8;
    const int vsw  = (tid & 7) << 3;

    // K DMA lane mapping: chunk c -> row c>>3, global k-chunk (c&7)^(row&7)
    const int kc0 = wave * 128 + lane;
    const int kr0 = kc0 >> 3;
    const int kkg = ((kc0 & 7) ^ (kr0 & 7)) * 8;

    short8 qf[2][2];
    #pragma unroll
    for (int i = 0; i < 2; ++i)
        #pragma unroll
        for (int kh = 0; kh < 2; ++kh)
            qf[i][kh] = *(const short8*)(qkv +
                (size_t)(b * L_SEQ + q0 + i * 16 + fm) * 1152 + h * HD + kh * 32 + quad * 8);

    floatx4 acc[2][4];
    float l_part[2][4];
    #pragma unroll
    for (int i = 0; i < 2; ++i) {
        #pragma unroll
        for (int j = 0; j < 4; ++j) acc[i][j] = (floatx4){0.f, 0.f, 0.f, 0.f};
        #pragma unroll
        for (int r = 0; r < 4; ++r) l_part[i][r] = 0.f;
    }

    for (int kt = kt0; kt < kt1; ++kt) {
        const int kv0 = kt * 64;
        __syncthreads();
        // K via async DMA (swizzled)
        gld_lds16(qkv + (size_t)(b * L_SEQ + kv0 + kr0) * 1152 + NDIM + kkg,
                  &Ks[(wave * 128) * 8]);
        gld_lds16(qkv + (size_t)(b * L_SEQ + kv0 + kr0 + 8) * 1152 + NDIM + kkg,
                  &Ks[(wave * 128 + 64) * 8]);
        // V transpose-scatter (register path)
        #pragma unroll
        for (int pass = 0; pass < 2; ++pass) {
            int row = srow + pass * 32;
            const ushort* vp = qkv + (size_t)(b * L_SEQ + kv0 + row) * 1152 + NDIM + HD + scol;
            short8 t = *(const short8*)vp;
            int mw = row ^ vsw;
            #pragma unroll
            for (int i2 = 0; i2 < 8; ++i2) Vt[(scol + i2) * 72 + mw] = (ushort)t[i2];
        }
        __syncthreads();

        floatx4 sp[2][4];
        #pragma unroll
        for (int j = 0; j < 4; ++j) {
            int rowk = j * 16 + fm;
            int s0 = (quad ^ (rowk & 7)) * 8;
            int s1 = ((4 + quad) ^ (rowk & 7)) * 8;
            short8 kf0 = *(const short8*)&Ks[rowk * 64 + s0];
            short8 kf1 = *(const short8*)&Ks[rowk * 64 + s1];
            #pragma unroll
            for (int i = 0; i < 2; ++i) {
                floatx4 z = (floatx4){0.f, 0.f, 0.f, 0.f};
                z = __builtin_amdgcn_mfma_f32_16x16x32_bf16(qf[i][0], kf0, z, 0, 0, 0);
                z = __builtin_amdgcn_mfma_f32_16x16x32_bf16(qf[i][1], kf1, z, 0, 0, 0);
                sp[i][j] = z;
            }
        }

        const bool diag = (kt == nkv - 1);
        #pragma unroll
        for (int i = 0; i < 2; ++i)
            #pragma unroll
            for (int j = 0; j < 4; ++j) {
                int col = kv0 + j * 16 + fm;
                #pragma unroll
                for (int r = 0; r < 4; ++r) {
                    // p = exp(s/8) = exp2(s * 0.125*log2e)
                    float p = exp2f(sp[i][j][r] * 0.18033688f);
                    if (diag) {
                        int rowg = q0 + i * 16 + quad * 4 + r;
                        if (col > rowg) p = 0.f;
                    }
                    sp[i][j][r] = p;
                    l_part[i][r] += p;
                }
            }

        #pragma unroll
        for (int i = 0; i < 2; ++i)
            #pragma unroll
            for (int j = 0; j < 4; ++j)
                #pragma unroll
                for (int r = 0; r < 4; ++r)
                    Ps[wave][(i * 16 + quad * 4 + r) * 72 + j * 16 + fm] = f2bf(sp[i][j][r]);

        short8 pf[2][2];
        #pragma unroll
        for (int i = 0; i < 2; ++i) {
            pf[i][0] = *(const short8*)&Ps[wave][(i * 16 + fm) * 72 + quad * 8];
            pf[i][1] = *(const short8*)&Ps[wave][(i * 16 + fm) * 72 + 32 + quad * 8];
        }

        #pragma unroll
        for (int dj = 0; dj < 4; ++dj) {
            int d = dj * 16 + fm;
            int sw8 = ((d >> 3) & 7) << 3;
            short8 vf0 = *(const short8*)&Vt[d * 72 + ((quad * 8) ^ sw8)];
            short8 vf1 = *(const short8*)&Vt[d * 72 + ((32 + quad * 8) ^ sw8)];
            #pragma unroll
            for (int i = 0; i < 2; ++i) {
                acc[i][dj] = __builtin_amdgcn_mfma_f32_16x16x32_bf16(pf[i][0], vf0, acc[i][dj], 0, 0, 0);
                acc[i][dj] = __builtin_amdgcn_mfma_f32_16x16x32_bf16(pf[i][1], vf1, acc[i][dj], 0, 0, 0);
            }
        }
    }

    float l_red[2][4];
    #pragma unroll
    for (int i = 0; i < 2; ++i)
        #pragma unroll
        for (int r = 0; r < 4; ++r) {
            float rs = l_part[i][r];
            rs += __shfl_xor(rs, 1, 16);
            rs += __shfl_xor(rs, 2, 16);
            rs += __shfl_xor(rs, 4, 16);
            rs += __shfl_xor(rs, 8, 16);
            l_red[i][r] = rs;
        }

    if (nsplit == 1) {
        #pragma unroll
        for (int i = 0; i < 2; ++i) {
            float inv[4];
            #pragma unroll
            for (int r = 0; r < 4; ++r) inv[r] = 1.f / l_red[i][r];
            #pragma unroll
            for (int dj = 0; dj < 4; ++dj)
                #pragma unroll
                for (int r = 0; r < 4; ++r) {
                    int q = q0 + i * 16 + quad * 4 + r;
                    att[(size_t)(b * L_SEQ + q) * NDIM + h * HD + dj * 16 + fm] =
                        f2bf(acc[i][dj][r] * inv[r]);
                }
        }
    } else {
        size_t pbase = ((size_t)((s * 2 + b) * 16 + h)) * L_SEQ;
        #pragma unroll
        for (int i = 0; i < 2; ++i)
            #pragma unroll
            for (int dj = 0; dj < 4; ++dj)
                #pragma unroll
                for (int r = 0; r < 4; ++r) {
                    int q = q0 + i * 16 + quad * 4 + r;
                    partO[(pbase + q) * 64 + dj * 16 + fm] = f2bf(acc[i][dj][r]);
                }
        if (fm == 0) {
            #pragma unroll
            for (int i = 0; i < 2; ++i)
                #pragma unroll
                for (int r = 0; r < 4; ++r)
                    partL[pbase + q0 + i * 16 + quad * 4 + r] = l_red[i][r];
        }
    }
}

// ---------------------------------------------------------------------------
// combine attention split partials for q >= 512.
// ---------------------------------------------------------------------------
__global__ __launch_bounds__(256) void attn_combine(
    const ushort* __restrict__ partO, const float* __restrict__ partL,
    ushort* __restrict__ att)
{
    int gid = blockIdx.x * 256 + threadIdx.x;
    int t8 = gid & 7;
    int row = gid >> 3;
    int q  = 512 + (row % 1536);
    int bh = row / 1536;
    int b = bh >> 4, h = bh & 15;
    int nsplit = (((q >> 5) >> 1) + 1 + SPLIT_KT - 1) / SPLIT_KT;

    float sum[8] = {0.f, 0.f, 0.f, 0.f, 0.f, 0.f, 0.f, 0.f};
    float L = 0.f;
    for (int s = 0; s < nsplit; ++s) {
        size_t pbase = ((size_t)((s * 2 + b) * 16 + h)) * L_SEQ + q;
        L += partL[pbase];
        short8 o = *(const short8*)&partO[pbase * 64 + t8 * 8];
        #pragma unroll
        for (int k = 0; k < 8; ++k) sum[k] += bf2f((ushort)o[k]);
    }
    float inv = 1.f / L;
    short8 outv;
    #pragma unroll
    for (int k = 0; k < 8; ++k) outv[k] = (short)f2bf(sum[k] * inv);
    *(short8*)&att[((size_t)(b * L_SEQ + q)) * NDIM + h * HD + t8 * 8] = outv;
}

// ---------------------------------------------------------------------------
// depthwise conv (window 4, left pad 3) + bias + silu.
// ---------------------------------------------------------------------------
__global__ __launch_bounds__(256) void conv_silu(
    const ushort* __restrict__ xr, const float* __restrict__ conv_w,
    const float* __restrict__ conv_b, ushort* __restrict__ u)
{
    const int idx = blockIdx.x * 256 + threadIdx.x;
    const int c  = idx & (DINNER - 1);
    const int bl = idx >> 11;
    const int l  = bl & (L_SEQ - 1);

    float acc = conv_b[c];
    #pragma unroll
    for (int j = 0; j < DCONV; ++j) {
        int ls = l - 3 + j;
        if (ls >= 0)
            acc += bf2f(xr[(size_t)(bl - 3 + j) * (2 * DINNER) + c]) * conv_w[c * DCONV + j];
    }
    u[idx] = f2bf(silu_f(acc));
}

// ---------------------------------------------------------------------------
// Chunked selective scan, phase 1.
// ---------------------------------------------------------------------------
__global__ __launch_bounds__(256) void scan_phase1(
    const ushort* __restrict__ delta, const ushort* __restrict__ u,
    const ushort* __restrict__ xdbl, const float* __restrict__ A_log,
    float* __restrict__ Hend, float* __restrict__ Sdt)
{
    const int idx = blockIdx.x * 256 + threadIdx.x;
    const int d = idx & (DINNER - 1);
    const int b = (idx >> 11) & (BATCH - 1);
    const int c = idx >> 12;

    float Av[DSTATE], h[DSTATE];
    #pragma unroll
    for (int n = 0; n < DSTATE; ++n) {
        Av[n] = -__expf(A_log[d * DSTATE + n]);
        h[n] = 0.f;
    }

    const int t0 = c * CHUNK;
    size_t bd = ((size_t)b * L_SEQ + t0) * DINNER + d;
    size_t bx = ((size_t)b * L_SEQ + t0) * 96 + DTRANK;
    float sdt = 0.f;

    for (int t = 0; t < CHUNK; ++t) {
        float dt = bf2f(delta[bd]);
        float uv = bf2f(u[bd]);
        sdt += dt;
        float du = dt * uv;
        short8 B0 = *(const short8*)&xdbl[bx];
        short8 B1 = *(const short8*)&xdbl[bx + 8];
        #pragma unroll
        for (int n = 0; n < 8; ++n)
            h[n] = __expf(dt * Av[n]) * h[n] + du * bf2f((ushort)B0[n]);
        #pragma unroll
        for (int n = 0; n < 8; ++n)
            h[8 + n] = __expf(dt * Av[8 + n]) * h[8 + n] + du * bf2f((ushort)B1[n]);
        bd += DINNER; bx += 96;
    }

    size_t ho = (((size_t)c * BATCH + b) * DINNER + d) * DSTATE;
    #pragma unroll
    for (int n = 0; n < DSTATE; n += 4)
        *(floatx4*)&Hend[ho + n] = (floatx4){h[n], h[n + 1], h[n + 2], h[n + 3]};
    Sdt[((size_t)c * BATCH + b) * DINNER + d] = sdt;
}

// ---------------------------------------------------------------------------
// phase 2: in-place exclusive combine over 64 chunks.
// ---------------------------------------------------------------------------
__global__ __launch_bounds__(256) void scan_phase2(
    float* __restrict__ H, const float* __restrict__ Sdt,
    const float* __restrict__ A_log)
{
    const int idx = blockIdx.x * 256 + threadIdx.x;
    const int n = idx & (DSTATE - 1);
    const int d = (idx >> 4) & (DINNER - 1);
    const int b = idx >> 15;

    const float Av = -__expf(A_log[d * DSTATE + n]);
    float hin = 0.f;
    for (int c = 0; c < NCHUNK; ++c) {
        size_t o  = (((size_t)c * BATCH + b) * DINNER + d) * DSTATE + n;
        float e   = H[o];
        float dAc = __expf(Av * Sdt[((size_t)c * BATCH + b) * DINNER + d]);
        H[o] = hin;
        hin = dAc * hin + e;
    }
}

// ---------------------------------------------------------------------------
// phase 3: redo chunk scan from Hin, emit y, fused ymod.
// ---------------------------------------------------------------------------
__global__ __launch_bounds__(256) void scan_phase3(
    const ushort* __restrict__ delta, const ushort* __restrict__ u,
    const ushort* __restrict__ xdbl, const float* __restrict__ A_log,
    const float* __restrict__ Hin, const float* __restrict__ Dp,
    const ushort* __restrict__ xr, ushort* __restrict__ yb)
{
    const int idx = blockIdx.x * 256 + threadIdx.x;
    const int d = idx & (DINNER - 1);
    const int b = (idx >> 11) & (BATCH - 1);
    const int c = idx >> 12;

    float Av[DSTATE], h[DSTATE];
    size_t ho = (((size_t)c * BATCH + b) * DINNER + d) * DSTATE;
    #pragma unroll
    for (int n = 0; n < DSTATE; n += 4) {
        floatx4 hv = *(const floatx4*)&Hin[ho + n];
        h[n] = hv[0]; h[n + 1] = hv[1]; h[n + 2] = hv[2]; h[n + 3] = hv[3];
    }
    #pragma unroll
    for (int n = 0; n < DSTATE; ++n)
        Av[n] = -__expf(A_log[d * DSTATE + n]);

    const float Dpd = Dp[d];
    const int t0 = c * CHUNK;
    size_t bd = ((size_t)b * L_SEQ + t0) * DINNER + d;
    size_t bx = ((size_t)b * L_SEQ + t0) * 96 + DTRANK;
    size_t br = ((size_t)b * L_SEQ + t0) * (2 * DINNER) + DINNER + d;

    for (int t = 0; t < CHUNK; ++t) {
        float dt = bf2f(delta[bd]);
        float uv = bf2f(u[bd]);
        float du = dt * uv;
        short8 B0 = *(const short8*)&xdbl[bx];
        short8 B1 = *(const short8*)&xdbl[bx + 8];
        short8 C0 = *(const short8*)&xdbl[bx + 16];
        short8 C1 = *(const short8*)&xdbl[bx + 24];
        float y = 0.f;
        #pragma unroll
        for (int n = 0; n < 8; ++n) {
            h[n] = __expf(dt * Av[n]) * h[n] + du * bf2f((ushort)B0[n]);
            y += h[n] * bf2f((ushort)C0[n]);
        }
        #pragma unroll
        for (int n = 0; n < 8; ++n) {
            h[8 + n] = __expf(dt * Av[8 + n]) * h[8 + n] + du * bf2f((ushort)B1[n]);
            y += h[8 + n] * bf2f((ushort)C1[n]);
        }
        float yv = y + uv * Dpd;
        float r  = bf2f(xr[br]);
        yb[bd] = f2bf(yv * silu_f(r));
        bd += DINNER; bx += 96; br += 2 * DINNER;
    }
}

// ---------------------------------------------------------------------------
extern "C" void kernel_launch(void* const* d_in, const int* in_sizes, int n_in,
                              void* d_out, int out_size, void* d_ws, size_t ws_size,
                              hipStream_t stream) {
    const void* x_raw      = d_in[0];
    const void* wqkv_raw   = d_in[1];
    const void* bqkv_raw   = d_in[2];
    const void* wao_raw    = d_in[3];
    const void* bao_raw    = d_in[4];
    const void* win_raw    = d_in[5];
    const void* convw_raw  = d_in[6];
    const void* convb_raw  = d_in[7];
    const void* wxp_raw    = d_in[8];
    const void* wdt_raw    = d_in[9];
    const void* bdt_raw    = d_in[10];
    const void* Alog_raw   = d_in[11];
    const void* Dp_raw     = d_in[12];
    const void* wout_raw   = d_in[13];

    const int M = BATCH * L_SEQ;  // 4096

    char* p = (char*)d_ws;
    size_t off = 0;
    auto A_ = [&](size_t bytes) { void* q = p + off; off += (bytes + 255) & ~255ull; return q; };

    ushort* x_b    = (ushort*)A_((size_t)M * NDIM * 2);
    ushort* wqkv_t = (ushort*)A_((size_t)NDIM * 1152 * 2);
    ushort* wao_t  = (ushort*)A_((size_t)NDIM * NDIM * 2);
    ushort* win_t  = (ushort*)A_((size_t)NDIM * 4096 * 2);
    float*  psum   = (float*)x_b;
    ushort* yb     = x_b;
    float*  Sdt    = (float*)(x_b + (size_t)M * DINNER);

    ushort* qkv    = (ushort*)A_((size_t)M * 1152 * 2);
    ushort* att    = (ushort*)A_((size_t)M * NDIM * 2);
    float*  Hend   = (float*)qkv;

    ushort* delta_b = (ushort*)A_((size_t)M * DINNER * 2);

    ushort* wxp_t  = (ushort*)A_((size_t)128 * DINNER * 2);
    ushort* wdt_t  = (ushort*)A_((size_t)DTRANK * DINNER * 2);
    ushort* wout_t = (ushort*)A_((size_t)DINNER * NDIM * 2);
    float*  bqkv_f = (float*)A_(1152 * 4);
    float*  bao_f  = (float*)A_(NDIM * 4);
    float*  convw_f= (float*)A_((size_t)DINNER * DCONV * 4);
    float*  convb_f= (float*)A_(DINNER * 4);
    float*  bdt_f  = (float*)A_(DINNER * 4);
    float*  Alog_f = (float*)A_((size_t)DINNER * DSTATE * 4);
    float*  Dp_f   = (float*)A_(DINNER * 4);
    int*    flag   = (int*)A_(256);
    ushort* x1b    = (ushort*)A_((size_t)M * NDIM * 2);
    ushort* xr     = (ushort*)A_((size_t)M * 4096 * 2);
    ushort* u      = (ushort*)A_((size_t)M * DINNER * 2);
    ushort* xdbl   = (ushort*)A_((size_t)M * 96 * 2);

    ushort* partO = xr;
    float*  partL = (float*)u;

    dim3 blk(256);

    // 0. one-launch prep (probe + x cvt + 6 transposes + pad + small params)
    prep_kernel<<<dim3(25473), blk, 0, stream>>>(
        x_raw, wqkv_raw, wao_raw, win_raw, wxp_raw, wdt_raw, wout_raw,
        bqkv_raw, bao_raw, convw_raw, convb_raw, bdt_raw, Alog_raw, Dp_raw,
        x_b, wqkv_t, wao_t, win_t, wxp_t, wdt_t, wout_t,
        bqkv_f, bao_f, convw_f, convb_f, bdt_f, Alog_f, Dp_f, flag);

    // 1. qkv = x @ wqkv + bqkv   (swap=0)
    gemm128<<<dim3(1152 / 128, M / 128), blk, 0, stream>>>(
        x_b, NDIM, wqkv_t, bqkv_f, nullptr, qkv, nullptr, nullptr, 1152, NDIM, 0, NDIM, nullptr, 0);

    // 2. flash attention (split-KV) + combine
    flash_attn_split<<<dim3(L_SEQ / 32, NHEADS / 4, BATCH * 4), blk, 0, stream>>>(
        qkv, att, partO, partL);
    attn_combine<<<dim3(1536), blk, 0, stream>>>(partO, partL, att);

    // 3. x1 = att @ w_ao + b_ao + x   (swap=0)
    gemm128<<<dim3(NDIM / 128, M / 128), blk, 0, stream>>>(
        att, NDIM, wao_t, bao_f, x_b, x1b, nullptr, nullptr, NDIM, NDIM, 0, NDIM, nullptr, 0);

    // 4. xr = x1 @ w_in   (swap=1: XCD-local A-strip)
    gemm128<<<dim3(M / 128, 4096 / 128), blk, 0, stream>>>(
        x1b, NDIM, win_t, nullptr, nullptr, xr, nullptr, nullptr, 4096, NDIM, 0, NDIM, nullptr, 1);

    // 5. conv + silu -> u
    conv_silu<<<dim3(M * DINNER / 256), blk, 0, stream>>>(xr, convw_f, convb_f, u);

    // 6. xdbl = u @ w_xproj  (split-K=8 over padded N=128)
    gemm128<<<dim3(1, M / 128, 8), blk, 0, stream>>>(
        u, DINNER, wxp_t, nullptr, nullptr, nullptr, nullptr, nullptr, 128, DINNER, 0, DINNER / 8, psum, 0);
    combine_xdbl<<<dim3(M * 96 / 256), blk, 0, stream>>>(psum, xdbl);

    // 7. delta = softplus(xdbl[:, :64] @ w_dt + b_dt)  (swap=0)
    gemm128<<<dim3(DINNER / 128, M / 128), blk, 0, stream>>>(
        xdbl, 96, wdt_t, bdt_f, nullptr, delta_b, nullptr, nullptr, DINNER, DTRANK, 1, DTRANK, nullptr, 0);

    // 8. chunked selective scan (+fused ymod) -> yb
    scan_phase1<<<dim3(NCHUNK * BATCH * DINNER / 256), blk, 0, stream>>>(
        delta_b, u, xdbl, Alog_f, Hend, Sdt);
    scan_phase2<<<dim3(BATCH * DINNER * DSTATE / 256), blk, 0, stream>>>(
        Hend, Sdt, Alog_f);
    scan_phase3<<<dim3(NCHUNK * BATCH * DINNER / 256), blk, 0, stream>>>(
        delta_b, u, xdbl, Alog_f, Hend, Dp_f, xr, yb);

    // 10. out = yb @ w_out + x1  (swap=1)
    gemm128<<<dim3(M / 128, NDIM / 128), blk, 0, stream>>>(
        yb, DINNER, wout_t, nullptr, x1b, (ushort*)d_out, (float*)d_out, flag, NDIM, DINNER, 0, DINNER, nullptr, 1);
}

// Round 12
// 534.572 us; speedup vs baseline: 1.1665x; 1.0070x over previous
//
#include <hip/hip_runtime.h>

#define L_SEQ   2048
#define BATCH   2
#define NDIM    1024
#define NHEADS  16
#define HD      64
#define DSTATE  16
#define DCONV   4
#define DINNER  2048
#define DTRANK  64
#define CHUNK   32
#define NCHUNK  (L_SEQ / CHUNK)   // 64
#define SPLIT_KT 8                // KV tiles per attention split

typedef short  short8  __attribute__((ext_vector_type(8)));
typedef float  floatx4 __attribute__((ext_vector_type(4)));

#define AS1 __attribute__((address_space(1)))
#define AS3 __attribute__((address_space(3)))

__device__ __forceinline__ float bf2f(ushort u) {
    union { uint i; float f; } v; v.i = ((uint)u) << 16; return v.f;
}
__device__ __forceinline__ ushort f2bf(float f) {
    uint x = __float_as_uint(f);
    uint r = (x + 0x7fffu + ((x >> 16) & 1u)) >> 16;
    return (ushort)r;
}
__device__ __forceinline__ float silu_f(float x) {
    return x / (1.f + __expf(-x));
}
__device__ __forceinline__ void gld_lds16(const void* g, void* l) {
    __builtin_amdgcn_global_load_lds((const AS1 uint*)g, (AS3 uint*)l, 16, 0, 0);
}
__device__ __forceinline__ float cvt_one(const void* s, int i, int f) {
    return f ? ((const float*)s)[i] : bf2f(((const ushort*)s)[i]);
}

// ---------------------------------------------------------------------------
// MEGA PREP: one launch: dtype-probe (per-block), x convert, 6 weight
// transposes, wxp pad, small-param f32 conversion.
// ---------------------------------------------------------------------------
__global__ __launch_bounds__(256) void prep_kernel(
    const void* __restrict__ x_raw,
    const void* __restrict__ wqkv, const void* __restrict__ wao,
    const void* __restrict__ win,  const void* __restrict__ wxp,
    const void* __restrict__ wdt,  const void* __restrict__ wout,
    const void* __restrict__ bqkv, const void* __restrict__ bao,
    const void* __restrict__ convw, const void* __restrict__ convb,
    const void* __restrict__ bdt,  const void* __restrict__ Alog,
    const void* __restrict__ Dp,
    ushort* __restrict__ x_b, ushort* __restrict__ wqkv_t,
    ushort* __restrict__ wao_t, ushort* __restrict__ win_t,
    ushort* __restrict__ wxp_t, ushort* __restrict__ wdt_t,
    ushort* __restrict__ wout_t,
    float* __restrict__ bqkv_f, float* __restrict__ bao_f,
    float* __restrict__ convw_f, float* __restrict__ convb_f,
    float* __restrict__ bdt_f, float* __restrict__ Alog_f,
    float* __restrict__ Dp_f, int* __restrict__ flag)
{
    __shared__ int cnt;
    __shared__ float tile[32][33];
    if (threadIdx.x == 0) cnt = 0;
    __syncthreads();
    {
        ushort w = ((const ushort*)x_raw)[threadIdx.x];
        int e = (w >> 7) & 0xff;
        if (w != 0 && (e < 100 || e > 140)) atomicAdd(&cnt, 1);
    }
    __syncthreads();
    const int f = (cnt >= 16) ? 1 : 0;
    if (blockIdx.x == 0 && threadIdx.x == 0) *flag = f;

    int id = blockIdx.x;
    if (id < 16384) {                               // x convert
        int i = id * 256 + threadIdx.x;
        x_b[i] = f2bf(cvt_one(x_raw, i, f));
        return;
    }
    id -= 16384;

    const void* src = nullptr; ushort* dst = nullptr; int K = 0, N = 0;
    if (id < 1152)                     { src = wqkv; dst = wqkv_t; K = 1024; N = 1152; }
    else if ((id -= 1152) < 1024)      { src = wao;  dst = wao_t;  K = 1024; N = 1024; }
    else if ((id -= 1024) < 4096)      { src = win;  dst = win_t;  K = 1024; N = 4096; }
    else if ((id -= 4096) < 192)       { src = wxp;  dst = wxp_t;  K = 2048; N = 96;   }
    else if ((id -= 192)  < 128)       { src = wdt;  dst = wdt_t;  K = 64;   N = 2048; }
    else if ((id -= 128)  < 2048)      { src = wout; dst = wout_t; K = 2048; N = 1024; }
    else {
        id -= 2048;
        if (id < 256) {                              // wxp pad rows 96..127
            wxp_t[(size_t)96 * DINNER + id * 256 + threadIdx.x] = 0;
        } else {                                     // small params
            int i = (id - 256) * 256 + threadIdx.x;
            if      (i < 1152)   bqkv_f[i]          = cvt_one(bqkv,  i,          f);
            else if (i < 2176)   bao_f[i - 1152]    = cvt_one(bao,   i - 1152,   f);
            else if (i < 10368)  convw_f[i - 2176]  = cvt_one(convw, i - 2176,   f);
            else if (i < 12416)  convb_f[i - 10368] = cvt_one(convb, i - 10368,  f);
            else if (i < 14464)  bdt_f[i - 12416]   = cvt_one(bdt,   i - 12416,  f);
            else if (i < 47232)  Alog_f[i - 14464]  = cvt_one(Alog,  i - 14464,  f);
            else if (i < 49280)  Dp_f[i - 47232]    = cvt_one(Dp,    i - 47232,  f);
        }
        return;
    }

    const int ntn = N / 32;
    const int n0 = (id % ntn) * 32, k0 = (id / ntn) * 32;
    const int tx = threadIdx.x & 31, ty = threadIdx.x >> 5;
    #pragma unroll
    for (int r = 0; r < 4; ++r) {
        size_t o = (size_t)(k0 + ty + r * 8) * N + n0 + tx;
        tile[ty + r * 8][tx] = cvt_one(src, (int)o, f);
    }
    __syncthreads();
    #pragma unroll
    for (int r = 0; r < 4; ++r) {
        int n = n0 + ty + r * 8;
        dst[(size_t)n * K + k0 + tx] = f2bf(tile[tx][ty + r * 8]);
    }
}

// ---------------------------------------------------------------------------
// MFMA GEMM: 128x128 tile, BK=64, XOR k-slot swizzle; swap per R9 evidence.
// ---------------------------------------------------------------------------
__global__ __launch_bounds__(256) void gemm128(
    const ushort* __restrict__ A, int lda,
    const ushort* __restrict__ Wt,
    const float* __restrict__ bias,
    const ushort* __restrict__ resb,
    ushort* __restrict__ outb, float* __restrict__ outf,
    const int* __restrict__ dtflag,
    int N, int K, int act, int klen, float* __restrict__ psum, int swap)
{
    __shared__ __align__(16) ushort As[128 * 64];
    __shared__ __align__(16) ushort Bs[128 * 64];

    const int tid  = threadIdx.x;
    const int wave = tid >> 6;
    const int lane = tid & 63;
    const int wm = (wave >> 1) * 64;
    const int wn = (wave & 1) * 64;
    const int fm = lane & 15;
    const int quad = lane >> 4;
    const int m0 = (swap ? blockIdx.x : blockIdx.y) * 128;
    const int n0 = (swap ? blockIdx.y : blockIdx.x) * 128;

    floatx4 acc[4][4];
    #pragma unroll
    for (int i = 0; i < 4; ++i)
        #pragma unroll
        for (int j = 0; j < 4; ++j) acc[i][j] = (floatx4){0.f, 0.f, 0.f, 0.f};

    int rowv[4], kgv[4];
    #pragma unroll
    for (int j = 0; j < 4; ++j) {
        int c = wave * 256 + j * 64 + lane;
        rowv[j] = c >> 3;
        kgv[j]  = (((c & 7) ^ ((c >> 3) & 7))) * 8;
    }

    const int kbeg = psum ? (blockIdx.z * klen) : 0;
    const int kend = kbeg + klen;

    for (int k0 = kbeg; k0 < kend; k0 += 64) {
        #pragma unroll
        for (int j = 0; j < 4; ++j)
            gld_lds16(A  + (size_t)(m0 + rowv[j]) * lda + k0 + kgv[j],
                      &As[(wave * 256 + j * 64) * 8]);
        #pragma unroll
        for (int j = 0; j < 4; ++j)
            gld_lds16(Wt + (size_t)(n0 + rowv[j]) * K   + k0 + kgv[j],
                      &Bs[(wave * 256 + j * 64) * 8]);
        __syncthreads();

        #pragma unroll
        for (int h = 0; h < 2; ++h) {
            short8 af[4], bf[4];
            #pragma unroll
            for (int i = 0; i < 4; ++i) {
                int row = wm + i * 16 + fm;
                int slot = (h * 4 + quad) ^ (row & 7);
                af[i] = *(const short8*)&As[row * 64 + slot * 8];
            }
            #pragma unroll
            for (int j = 0; j < 4; ++j) {
                int row = wn + j * 16 + fm;
                int slot = (h * 4 + quad) ^ (row & 7);
                bf[j] = *(const short8*)&Bs[row * 64 + slot * 8];
            }
            #pragma unroll
            for (int i = 0; i < 4; ++i)
                #pragma unroll
                for (int j = 0; j < 4; ++j)
                    acc[i][j] = __builtin_amdgcn_mfma_f32_16x16x32_bf16(af[i], bf[j], acc[i][j], 0, 0, 0);
        }
        __syncthreads();
    }

    if (psum) {
        int mgrid = swap ? gridDim.x : gridDim.y;
        float* po = psum + (size_t)blockIdx.z * ((size_t)mgrid * 128) * N;
        #pragma unroll
        for (int j = 0; j < 4; ++j) {
            int col = n0 + wn + j * 16 + fm;
            #pragma unroll
            for (int i = 0; i < 4; ++i) {
                int rowb = m0 + wm + i * 16 + quad * 4;
                #pragma unroll
                for (int r = 0; r < 4; ++r)
                    po[(size_t)(rowb + r) * N + col] = acc[i][j][r];
            }
        }
        return;
    }

    const int flagv = dtflag ? *dtflag : 0;
    #pragma unroll
    for (int j = 0; j < 4; ++j) {
        int col = n0 + wn + j * 16 + fm;
        float bvv = bias ? bias[col] : 0.f;
        #pragma unroll
        for (int i = 0; i < 4; ++i) {
            int rowb = m0 + wm + i * 16 + quad * 4;
            #pragma unroll
            for (int r = 0; r < 4; ++r) {
                float v = acc[i][j][r] + bvv;
                if (act == 1)
                    v = fmaxf(v, 0.f) + __logf(1.f + __expf(-fabsf(v)));
                size_t o = (size_t)(rowb + r) * N + col;
                if (resb) v += bf2f(resb[o]);
                if (dtflag) {
                    if (flagv) outf[o] = v; else outb[o] = f2bf(v);
                } else {
                    if (outb) outb[o] = f2bf(v);
                    if (outf) outf[o] = v;
                }
            }
        }
    }
}

// ---------------------------------------------------------------------------
// combine split-K partials (4096 x 128 padded) -> xdbl bf16 (stride 96).
// ---------------------------------------------------------------------------
__global__ __launch_bounds__(256) void combine_xdbl(
    const float* __restrict__ psum, ushort* __restrict__ xdbl)
{
    int idx = blockIdx.x * 256 + threadIdx.x;
    int row = idx / 96, col = idx - row * 96;
    float s = 0.f;
    #pragma unroll
    for (int z = 0; z < 8; ++z)
        s += psum[(size_t)z * 4096 * 128 + row * 128 + col];
    xdbl[idx] = f2bf(s);
}

// ---------------------------------------------------------------------------
// Flash MQA attention, split-KV, static-max softmax (R10 register-path K
// staging — R11's K-DMA variant cost VGPR 84->120 and 10 us; reverted).
// ---------------------------------------------------------------------------
__global__ __launch_bounds__(256) void flash_attn_split(
    const ushort* __restrict__ qkv, ushort* __restrict__ att,
    ushort* __restrict__ partO, float* __restrict__ partL)
{
    __shared__ __align__(16) ushort Ks[64 * 72];
    __shared__ __align__(16) ushort Vt[64 * 72];
    __shared__ __align__(16) ushort Ps[4][32 * 72];

    const int tile = blockIdx.x;
    const int hg   = blockIdx.y;
    const int zz   = blockIdx.z;
    const int b = zz >> 2, s = zz & 3;
    const int q0 = tile * 32;
    const int nkv = (q0 >> 6) + 1;
    const int nsplit = (nkv + SPLIT_KT - 1) / SPLIT_KT;
    if (s >= nsplit) return;
    const int kt0 = s * SPLIT_KT;
    const int kt1 = (nkv < kt0 + SPLIT_KT) ? nkv : (kt0 + SPLIT_KT);

    const int tid  = threadIdx.x;
    const int wave = tid >> 6;
    const int lane = tid & 63;
    const int fm   = lane & 15;
    const int quad = lane >> 4;
    const int h    = hg * 4 + wave;

    const int srow = tid >> 3;
    const int scol = (tid & 7) * 8;
    const int vsw  = (tid & 7) << 3;

    short8 qf[2][2];
    #pragma unroll
    for (int i = 0; i < 2; ++i)
        #pragma unroll
        for (int kh = 0; kh < 2; ++kh)
            qf[i][kh] = *(const short8*)(qkv +
                (size_t)(b * L_SEQ + q0 + i * 16 + fm) * 1152 + h * HD + kh * 32 + quad * 8);

    floatx4 acc[2][4];
    float l_part[2][4];
    #pragma unroll
    for (int i = 0; i < 2; ++i) {
        #pragma unroll
        for (int j = 0; j < 4; ++j) acc[i][j] = (floatx4){0.f, 0.f, 0.f, 0.f};
        #pragma unroll
        for (int r = 0; r < 4; ++r) l_part[i][r] = 0.f;
    }

    for (int kt = kt0; kt < kt1; ++kt) {
        const int kv0 = kt * 64;
        __syncthreads();
        #pragma unroll
        for (int pass = 0; pass < 2; ++pass) {
            int row = srow + pass * 32;
            const ushort* kp = qkv + (size_t)(b * L_SEQ + kv0 + row) * 1152 + NDIM + scol;
            *(short8*)&Ks[row * 72 + scol] = *(const short8*)kp;
            short8 t = *(const short8*)(kp + HD);
            int mw = row ^ vsw;
            #pragma unroll
            for (int i2 = 0; i2 < 8; ++i2) Vt[(scol + i2) * 72 + mw] = (ushort)t[i2];
        }
        __syncthreads();

        floatx4 sp[2][4];
        #pragma unroll
        for (int j = 0; j < 4; ++j) {
            short8 kf0 = *(const short8*)&Ks[(j * 16 + fm) * 72 + quad * 8];
            short8 kf1 = *(const short8*)&Ks[(j * 16 + fm) * 72 + 32 + quad * 8];
            #pragma unroll
            for (int i = 0; i < 2; ++i) {
                floatx4 z = (floatx4){0.f, 0.f, 0.f, 0.f};
                z = __builtin_amdgcn_mfma_f32_16x16x32_bf16(qf[i][0], kf0, z, 0, 0, 0);
                z = __builtin_amdgcn_mfma_f32_16x16x32_bf16(qf[i][1], kf1, z, 0, 0, 0);
                sp[i][j] = z;
            }
        }

        const bool diag = (kt == nkv - 1);
        #pragma unroll
        for (int i = 0; i < 2; ++i)
            #pragma unroll
            for (int j = 0; j < 4; ++j) {
                int col = kv0 + j * 16 + fm;
                #pragma unroll
                for (int r = 0; r < 4; ++r) {
                    // p = exp(s/8) = exp2(s * 0.125*log2e)
                    float p = exp2f(sp[i][j][r] * 0.18033688f);
                    if (diag) {
                        int rowg = q0 + i * 16 + quad * 4 + r;
                        if (col > rowg) p = 0.f;
                    }
                    sp[i][j][r] = p;
                    l_part[i][r] += p;
                }
            }

        #pragma unroll
        for (int i = 0; i < 2; ++i)
            #pragma unroll
            for (int j = 0; j < 4; ++j)
                #pragma unroll
                for (int r = 0; r < 4; ++r)
                    Ps[wave][(i * 16 + quad * 4 + r) * 72 + j * 16 + fm] = f2bf(sp[i][j][r]);

        short8 pf[2][2];
        #pragma unroll
        for (int i = 0; i < 2; ++i) {
            pf[i][0] = *(const short8*)&Ps[wave][(i * 16 + fm) * 72 + quad * 8];
            pf[i][1] = *(const short8*)&Ps[wave][(i * 16 + fm) * 72 + 32 + quad * 8];
        }

        #pragma unroll
        for (int dj = 0; dj < 4; ++dj) {
            int d = dj * 16 + fm;
            int sw8 = ((d >> 3) & 7) << 3;
            short8 vf0 = *(const short8*)&Vt[d * 72 + ((quad * 8) ^ sw8)];
            short8 vf1 = *(const short8*)&Vt[d * 72 + ((32 + quad * 8) ^ sw8)];
            #pragma unroll
            for (int i = 0; i < 2; ++i) {
                acc[i][dj] = __builtin_amdgcn_mfma_f32_16x16x32_bf16(pf[i][0], vf0, acc[i][dj], 0, 0, 0);
                acc[i][dj] = __builtin_amdgcn_mfma_f32_16x16x32_bf16(pf[i][1], vf1, acc[i][dj], 0, 0, 0);
            }
        }
    }

    float l_red[2][4];
    #pragma unroll
    for (int i = 0; i < 2; ++i)
        #pragma unroll
        for (int r = 0; r < 4; ++r) {
            float rs = l_part[i][r];
            rs += __shfl_xor(rs, 1, 16);
            rs += __shfl_xor(rs, 2, 16);
            rs += __shfl_xor(rs, 4, 16);
            rs += __shfl_xor(rs, 8, 16);
            l_red[i][r] = rs;
        }

    if (nsplit == 1) {
        #pragma unroll
        for (int i = 0; i < 2; ++i) {
            float inv[4];
            #pragma unroll
            for (int r = 0; r < 4; ++r) inv[r] = 1.f / l_red[i][r];
            #pragma unroll
            for (int dj = 0; dj < 4; ++dj)
                #pragma unroll
                for (int r = 0; r < 4; ++r) {
                    int q = q0 + i * 16 + quad * 4 + r;
                    att[(size_t)(b * L_SEQ + q) * NDIM + h * HD + dj * 16 + fm] =
                        f2bf(acc[i][dj][r] * inv[r]);
                }
        }
    } else {
        size_t pbase = ((size_t)((s * 2 + b) * 16 + h)) * L_SEQ;
        #pragma unroll
        for (int i = 0; i < 2; ++i)
            #pragma unroll
            for (int dj = 0; dj < 4; ++dj)
                #pragma unroll
                for (int r = 0; r < 4; ++r) {
                    int q = q0 + i * 16 + quad * 4 + r;
                    partO[(pbase + q) * 64 + dj * 16 + fm] = f2bf(acc[i][dj][r]);
                }
        if (fm == 0) {
            #pragma unroll
            for (int i = 0; i < 2; ++i)
                #pragma unroll
                for (int r = 0; r < 4; ++r)
                    partL[pbase + q0 + i * 16 + quad * 4 + r] = l_red[i][r];
        }
    }
}

// ---------------------------------------------------------------------------
// combine attention split partials for q >= 512.
// ---------------------------------------------------------------------------
__global__ __launch_bounds__(256) void attn_combine(
    const ushort* __restrict__ partO, const float* __restrict__ partL,
    ushort* __restrict__ att)
{
    int gid = blockIdx.x * 256 + threadIdx.x;
    int t8 = gid & 7;
    int row = gid >> 3;
    int q  = 512 + (row % 1536);
    int bh = row / 1536;
    int b = bh >> 4, h = bh & 15;
    int nsplit = (((q >> 5) >> 1) + 1 + SPLIT_KT - 1) / SPLIT_KT;

    float sum[8] = {0.f, 0.f, 0.f, 0.f, 0.f, 0.f, 0.f, 0.f};
    float L = 0.f;
    for (int s = 0; s < nsplit; ++s) {
        size_t pbase = ((size_t)((s * 2 + b) * 16 + h)) * L_SEQ + q;
        L += partL[pbase];
        short8 o = *(const short8*)&partO[pbase * 64 + t8 * 8];
        #pragma unroll
        for (int k = 0; k < 8; ++k) sum[k] += bf2f((ushort)o[k]);
    }
    float inv = 1.f / L;
    short8 outv;
    #pragma unroll
    for (int k = 0; k < 8; ++k) outv[k] = (short)f2bf(sum[k] * inv);
    *(short8*)&att[((size_t)(b * L_SEQ + q)) * NDIM + h * HD + t8 * 8] = outv;
}

// ---------------------------------------------------------------------------
// depthwise conv (window 4, left pad 3) + bias + silu.
// ---------------------------------------------------------------------------
__global__ __launch_bounds__(256) void conv_silu(
    const ushort* __restrict__ xr, const float* __restrict__ conv_w,
    const float* __restrict__ conv_b, ushort* __restrict__ u)
{
    const int idx = blockIdx.x * 256 + threadIdx.x;
    const int c  = idx & (DINNER - 1);
    const int bl = idx >> 11;
    const int l  = bl & (L_SEQ - 1);

    float acc = conv_b[c];
    #pragma unroll
    for (int j = 0; j < DCONV; ++j) {
        int ls = l - 3 + j;
        if (ls >= 0)
            acc += bf2f(xr[(size_t)(bl - 3 + j) * (2 * DINNER) + c]) * conv_w[c * DCONV + j];
    }
    u[idx] = f2bf(silu_f(acc));
}

// ---------------------------------------------------------------------------
// Chunked selective scan, phase 1.
// ---------------------------------------------------------------------------
__global__ __launch_bounds__(256) void scan_phase1(
    const ushort* __restrict__ delta, const ushort* __restrict__ u,
    const ushort* __restrict__ xdbl, const float* __restrict__ A_log,
    float* __restrict__ Hend, float* __restrict__ Sdt)
{
    const int idx = blockIdx.x * 256 + threadIdx.x;
    const int d = idx & (DINNER - 1);
    const int b = (idx >> 11) & (BATCH - 1);
    const int c = idx >> 12;

    float Av[DSTATE], h[DSTATE];
    #pragma unroll
    for (int n = 0; n < DSTATE; ++n) {
        Av[n] = -__expf(A_log[d * DSTATE + n]);
        h[n] = 0.f;
    }

    const int t0 = c * CHUNK;
    size_t bd = ((size_t)b * L_SEQ + t0) * DINNER + d;
    size_t bx = ((size_t)b * L_SEQ + t0) * 96 + DTRANK;
    float sdt = 0.f;

    for (int t = 0; t < CHUNK; ++t) {
        float dt = bf2f(delta[bd]);
        float uv = bf2f(u[bd]);
        sdt += dt;
        float du = dt * uv;
        short8 B0 = *(const short8*)&xdbl[bx];
        short8 B1 = *(const short8*)&xdbl[bx + 8];
        #pragma unroll
        for (int n = 0; n < 8; ++n)
            h[n] = __expf(dt * Av[n]) * h[n] + du * bf2f((ushort)B0[n]);
        #pragma unroll
        for (int n = 0; n < 8; ++n)
            h[8 + n] = __expf(dt * Av[8 + n]) * h[8 + n] + du * bf2f((ushort)B1[n]);
        bd += DINNER; bx += 96;
    }

    size_t ho = (((size_t)c * BATCH + b) * DINNER + d) * DSTATE;
    #pragma unroll
    for (int n = 0; n < DSTATE; n += 4)
        *(floatx4*)&Hend[ho + n] = (floatx4){h[n], h[n + 1], h[n + 2], h[n + 3]};
    Sdt[((size_t)c * BATCH + b) * DINNER + d] = sdt;
}

// ---------------------------------------------------------------------------
// phase 2: in-place exclusive combine over 64 chunks.
// ---------------------------------------------------------------------------
__global__ __launch_bounds__(256) void scan_phase2(
    float* __restrict__ H, const float* __restrict__ Sdt,
    const float* __restrict__ A_log)
{
    const int idx = blockIdx.x * 256 + threadIdx.x;
    const int n = idx & (DSTATE - 1);
    const int d = (idx >> 4) & (DINNER - 1);
    const int b = idx >> 15;

    const float Av = -__expf(A_log[d * DSTATE + n]);
    float hin = 0.f;
    for (int c = 0; c < NCHUNK; ++c) {
        size_t o  = (((size_t)c * BATCH + b) * DINNER + d) * DSTATE + n;
        float e   = H[o];
        float dAc = __expf(Av * Sdt[((size_t)c * BATCH + b) * DINNER + d]);
        H[o] = hin;
        hin = dAc * hin + e;
    }
}

// ---------------------------------------------------------------------------
// phase 3: redo chunk scan from Hin, emit y, fused ymod.
// ---------------------------------------------------------------------------
__global__ __launch_bounds__(256) void scan_phase3(
    const ushort* __restrict__ delta, const ushort* __restrict__ u,
    const ushort* __restrict__ xdbl, const float* __restrict__ A_log,
    const float* __restrict__ Hin, const float* __restrict__ Dp,
    const ushort* __restrict__ xr, ushort* __restrict__ yb)
{
    const int idx = blockIdx.x * 256 + threadIdx.x;
    const int d = idx & (DINNER - 1);
    const int b = (idx >> 11) & (BATCH - 1);
    const int c = idx >> 12;

    float Av[DSTATE], h[DSTATE];
    size_t ho = (((size_t)c * BATCH + b) * DINNER + d) * DSTATE;
    #pragma unroll
    for (int n = 0; n < DSTATE; n += 4) {
        floatx4 hv = *(const floatx4*)&Hin[ho + n];
        h[n] = hv[0]; h[n + 1] = hv[1]; h[n + 2] = hv[2]; h[n + 3] = hv[3];
    }
    #pragma unroll
    for (int n = 0; n < DSTATE; ++n)
        Av[n] = -__expf(A_log[d * DSTATE + n]);

    const float Dpd = Dp[d];
    const int t0 = c * CHUNK;
    size_t bd = ((size_t)b * L_SEQ + t0) * DINNER + d;
    size_t bx = ((size_t)b * L_SEQ + t0) * 96 + DTRANK;
    size_t br = ((size_t)b * L_SEQ + t0) * (2 * DINNER) + DINNER + d;

    for (int t = 0; t < CHUNK; ++t) {
        float dt = bf2f(delta[bd]);
        float uv = bf2f(u[bd]);
        float du = dt * uv;
        short8 B0 = *(const short8*)&xdbl[bx];
        short8 B1 = *(const short8*)&xdbl[bx + 8];
        short8 C0 = *(const short8*)&xdbl[bx + 16];
        short8 C1 = *(const short8*)&xdbl[bx + 24];
        float y = 0.f;
        #pragma unroll
        for (int n = 0; n < 8; ++n) {
            h[n] = __expf(dt * Av[n]) * h[n] + du * bf2f((ushort)B0[n]);
            y += h[n] * bf2f((ushort)C0[n]);
        }
        #pragma unroll
        for (int n = 0; n < 8; ++n) {
            h[8 + n] = __expf(dt * Av[8 + n]) * h[8 + n] + du * bf2f((ushort)B1[n]);
            y += h[8 + n] * bf2f((ushort)C1[n]);
        }
        float yv = y + uv * Dpd;
        float r  = bf2f(xr[br]);
        yb[bd] = f2bf(yv * silu_f(r));
        bd += DINNER; bx += 96; br += 2 * DINNER;
    }
}

// ---------------------------------------------------------------------------
extern "C" void kernel_launch(void* const* d_in, const int* in_sizes, int n_in,
                              void* d_out, int out_size, void* d_ws, size_t ws_size,
                              hipStream_t stream) {
    const void* x_raw      = d_in[0];
    const void* wqkv_raw   = d_in[1];
    const void* bqkv_raw   = d_in[2];
    const void* wao_raw    = d_in[3];
    const void* bao_raw    = d_in[4];
    const void* win_raw    = d_in[5];
    const void* convw_raw  = d_in[6];
    const void* convb_raw  = d_in[7];
    const void* wxp_raw    = d_in[8];
    const void* wdt_raw    = d_in[9];
    const void* bdt_raw    = d_in[10];
    const void* Alog_raw   = d_in[11];
    const void* Dp_raw     = d_in[12];
    const void* wout_raw   = d_in[13];

    const int M = BATCH * L_SEQ;  // 4096

    char* p = (char*)d_ws;
    size_t off = 0;
    auto A_ = [&](size_t bytes) { void* q = p + off; off += (bytes + 255) & ~255ull; return q; };

    ushort* x_b    = (ushort*)A_((size_t)M * NDIM * 2);
    ushort* wqkv_t = (ushort*)A_((size_t)NDIM * 1152 * 2);
    ushort* wao_t  = (ushort*)A_((size_t)NDIM * NDIM * 2);
    ushort* win_t  = (ushort*)A_((size_t)NDIM * 4096 * 2);
    float*  psum   = (float*)x_b;
    ushort* yb     = x_b;
    float*  Sdt    = (float*)(x_b + (size_t)M * DINNER);

    ushort* qkv    = (ushort*)A_((size_t)M * 1152 * 2);
    ushort* att    = (ushort*)A_((size_t)M * NDIM * 2);
    float*  Hend   = (float*)qkv;

    ushort* delta_b = (ushort*)A_((size_t)M * DINNER * 2);

    ushort* wxp_t  = (ushort*)A_((size_t)128 * DINNER * 2);
    ushort* wdt_t  = (ushort*)A_((size_t)DTRANK * DINNER * 2);
    ushort* wout_t = (ushort*)A_((size_t)DINNER * NDIM * 2);
    float*  bqkv_f = (float*)A_(1152 * 4);
    float*  bao_f  = (float*)A_(NDIM * 4);
    float*  convw_f= (float*)A_((size_t)DINNER * DCONV * 4);
    float*  convb_f= (float*)A_(DINNER * 4);
    float*  bdt_f  = (float*)A_(DINNER * 4);
    float*  Alog_f = (float*)A_((size_t)DINNER * DSTATE * 4);
    float*  Dp_f   = (float*)A_(DINNER * 4);
    int*    flag   = (int*)A_(256);
    ushort* x1b    = (ushort*)A_((size_t)M * NDIM * 2);
    ushort* xr     = (ushort*)A_((size_t)M * 4096 * 2);
    ushort* u      = (ushort*)A_((size_t)M * DINNER * 2);
    ushort* xdbl   = (ushort*)A_((size_t)M * 96 * 2);

    ushort* partO = xr;
    float*  partL = (float*)u;

    dim3 blk(256);

    // 0. one-launch prep (probe + x cvt + 6 transposes + pad + small params)
    prep_kernel<<<dim3(25473), blk, 0, stream>>>(
        x_raw, wqkv_raw, wao_raw, win_raw, wxp_raw, wdt_raw, wout_raw,
        bqkv_raw, bao_raw, convw_raw, convb_raw, bdt_raw, Alog_raw, Dp_raw,
        x_b, wqkv_t, wao_t, win_t, wxp_t, wdt_t, wout_t,
        bqkv_f, bao_f, convw_f, convb_f, bdt_f, Alog_f, Dp_f, flag);

    // 1. qkv = x @ wqkv + bqkv   (swap=0)
    gemm128<<<dim3(1152 / 128, M / 128), blk, 0, stream>>>(
        x_b, NDIM, wqkv_t, bqkv_f, nullptr, qkv, nullptr, nullptr, 1152, NDIM, 0, NDIM, nullptr, 0);

    // 2. flash attention (split-KV) + combine
    flash_attn_split<<<dim3(L_SEQ / 32, NHEADS / 4, BATCH * 4), blk, 0, stream>>>(
        qkv, att, partO, partL);
    attn_combine<<<dim3(1536), blk, 0, stream>>>(partO, partL, att);

    // 3. x1 = att @ w_ao + b_ao + x   (swap=0)
    gemm128<<<dim3(NDIM / 128, M / 128), blk, 0, stream>>>(
        att, NDIM, wao_t, bao_f, x_b, x1b, nullptr, nullptr, NDIM, NDIM, 0, NDIM, nullptr, 0);

    // 4. xr = x1 @ w_in   (swap=1: XCD-local A-strip)
    gemm128<<<dim3(M / 128, 4096 / 128), blk, 0, stream>>>(
        x1b, NDIM, win_t, nullptr, nullptr, xr, nullptr, nullptr, 4096, NDIM, 0, NDIM, nullptr, 1);

    // 5. conv + silu -> u
    conv_silu<<<dim3(M * DINNER / 256), blk, 0, stream>>>(xr, convw_f, convb_f, u);

    // 6. xdbl = u @ w_xproj  (split-K=8 over padded N=128)
    gemm128<<<dim3(1, M / 128, 8), blk, 0, stream>>>(
        u, DINNER, wxp_t, nullptr, nullptr, nullptr, nullptr, nullptr, 128, DINNER, 0, DINNER / 8, psum, 0);
    combine_xdbl<<<dim3(M * 96 / 256), blk, 0, stream>>>(psum, xdbl);

    // 7. delta = softplus(xdbl[:, :64] @ w_dt + b_dt)  (swap=0)
    gemm128<<<dim3(DINNER / 128, M / 128), blk, 0, stream>>>(
        xdbl, 96, wdt_t, bdt_f, nullptr, delta_b, nullptr, nullptr, DINNER, DTRANK, 1, DTRANK, nullptr, 0);

    // 8. chunked selective scan (+fused ymod) -> yb
    scan_phase1<<<dim3(NCHUNK * BATCH * DINNER / 256), blk, 0, stream>>>(
        delta_b, u, xdbl, Alog_f, Hend, Sdt);
    scan_phase2<<<dim3(BATCH * DINNER * DSTATE / 256), blk, 0, stream>>>(
        Hend, Sdt, Alog_f);
    scan_phase3<<<dim3(NCHUNK * BATCH * DINNER / 256), blk, 0, stream>>>(
        delta_b, u, xdbl, Alog_f, Hend, Dp_f, xr, yb);

    // 10. out = yb @ w_out + x1  (swap=1)
    gemm128<<<dim3(M / 128, NDIM / 128), blk, 0, stream>>>(
        yb, DINNER, wout_t, nullptr, x1b, (ushort*)d_out, (float*)d_out, flag, NDIM, DINNER, 0, DINNER, nullptr, 1);
}

// Round 13
// 529.184 us; speedup vs baseline: 1.1784x; 1.0102x over previous
//
#include <hip/hip_runtime.h>

#define L_SEQ   2048
#define BATCH   2
#define NDIM    1024
#define NHEADS  16
#define HD      64
#define DSTATE  16
#define DCONV   4
#define DINNER  2048
#define DTRANK  64
#define CHUNK   32
#define NCHUNK  (L_SEQ / CHUNK)   // 64
#define SPLIT_KT 8                // KV tiles per attention split

typedef short  short8  __attribute__((ext_vector_type(8)));
typedef float  floatx4 __attribute__((ext_vector_type(4)));

#define AS1 __attribute__((address_space(1)))
#define AS3 __attribute__((address_space(3)))

__device__ __forceinline__ float bf2f(ushort u) {
    union { uint i; float f; } v; v.i = ((uint)u) << 16; return v.f;
}
// bf16 convert: native v_cvt_pk_bf16_f32 (RNE, 1 VALU op) when available;
// manual RNE fallback (4 ops). [R13: manual f2bf was ~40% of flash VALU]
#if defined(__has_builtin) && __has_builtin(__builtin_amdgcn_cvt_pk_bf16_f32)
__device__ __forceinline__ ushort f2bf(float f) {
    auto p = __builtin_amdgcn_cvt_pk_bf16_f32(f, f);
    union { decltype(p) v; ushort u[2]; } cv; cv.v = p;
    return cv.u[0];
}
#else
__device__ __forceinline__ ushort f2bf(float f) {
    uint x = __float_as_uint(f);
    uint r = (x + 0x7fffu + ((x >> 16) & 1u)) >> 16;
    return (ushort)r;
}
#endif
__device__ __forceinline__ float silu_f(float x) {
    return x / (1.f + __expf(-x));
}
__device__ __forceinline__ void gld_lds16(const void* g, void* l) {
    __builtin_amdgcn_global_load_lds((const AS1 uint*)g, (AS3 uint*)l, 16, 0, 0);
}
__device__ __forceinline__ float cvt_one(const void* s, int i, int f) {
    return f ? ((const float*)s)[i] : bf2f(((const ushort*)s)[i]);
}

// ---------------------------------------------------------------------------
// MEGA PREP: one launch: dtype-probe (per-block), x convert, 6 weight
// transposes, wxp pad, small-param f32 conversion.
// ---------------------------------------------------------------------------
__global__ __launch_bounds__(256) void prep_kernel(
    const void* __restrict__ x_raw,
    const void* __restrict__ wqkv, const void* __restrict__ wao,
    const void* __restrict__ win,  const void* __restrict__ wxp,
    const void* __restrict__ wdt,  const void* __restrict__ wout,
    const void* __restrict__ bqkv, const void* __restrict__ bao,
    const void* __restrict__ convw, const void* __restrict__ convb,
    const void* __restrict__ bdt,  const void* __restrict__ Alog,
    const void* __restrict__ Dp,
    ushort* __restrict__ x_b, ushort* __restrict__ wqkv_t,
    ushort* __restrict__ wao_t, ushort* __restrict__ win_t,
    ushort* __restrict__ wxp_t, ushort* __restrict__ wdt_t,
    ushort* __restrict__ wout_t,
    float* __restrict__ bqkv_f, float* __restrict__ bao_f,
    float* __restrict__ convw_f, float* __restrict__ convb_f,
    float* __restrict__ bdt_f, float* __restrict__ Alog_f,
    float* __restrict__ Dp_f, int* __restrict__ flag)
{
    __shared__ int cnt;
    __shared__ float tile[32][33];
    if (threadIdx.x == 0) cnt = 0;
    __syncthreads();
    {
        ushort w = ((const ushort*)x_raw)[threadIdx.x];
        int e = (w >> 7) & 0xff;
        if (w != 0 && (e < 100 || e > 140)) atomicAdd(&cnt, 1);
    }
    __syncthreads();
    const int f = (cnt >= 16) ? 1 : 0;
    if (blockIdx.x == 0 && threadIdx.x == 0) *flag = f;

    int id = blockIdx.x;
    if (id < 16384) {                               // x convert
        int i = id * 256 + threadIdx.x;
        x_b[i] = f2bf(cvt_one(x_raw, i, f));
        return;
    }
    id -= 16384;

    const void* src = nullptr; ushort* dst = nullptr; int K = 0, N = 0;
    if (id < 1152)                     { src = wqkv; dst = wqkv_t; K = 1024; N = 1152; }
    else if ((id -= 1152) < 1024)      { src = wao;  dst = wao_t;  K = 1024; N = 1024; }
    else if ((id -= 1024) < 4096)      { src = win;  dst = win_t;  K = 1024; N = 4096; }
    else if ((id -= 4096) < 192)       { src = wxp;  dst = wxp_t;  K = 2048; N = 96;   }
    else if ((id -= 192)  < 128)       { src = wdt;  dst = wdt_t;  K = 64;   N = 2048; }
    else if ((id -= 128)  < 2048)      { src = wout; dst = wout_t; K = 2048; N = 1024; }
    else {
        id -= 2048;
        if (id < 256) {                              // wxp pad rows 96..127
            wxp_t[(size_t)96 * DINNER + id * 256 + threadIdx.x] = 0;
        } else {                                     // small params
            int i = (id - 256) * 256 + threadIdx.x;
            if      (i < 1152)   bqkv_f[i]          = cvt_one(bqkv,  i,          f);
            else if (i < 2176)   bao_f[i - 1152]    = cvt_one(bao,   i - 1152,   f);
            else if (i < 10368)  convw_f[i - 2176]  = cvt_one(convw, i - 2176,   f);
            else if (i < 12416)  convb_f[i - 10368] = cvt_one(convb, i - 10368,  f);
            else if (i < 14464)  bdt_f[i - 12416]   = cvt_one(bdt,   i - 12416,  f);
            else if (i < 47232)  Alog_f[i - 14464]  = cvt_one(Alog,  i - 14464,  f);
            else if (i < 49280)  Dp_f[i - 47232]    = cvt_one(Dp,    i - 47232,  f);
        }
        return;
    }

    const int ntn = N / 32;
    const int n0 = (id % ntn) * 32, k0 = (id / ntn) * 32;
    const int tx = threadIdx.x & 31, ty = threadIdx.x >> 5;
    #pragma unroll
    for (int r = 0; r < 4; ++r) {
        size_t o = (size_t)(k0 + ty + r * 8) * N + n0 + tx;
        tile[ty + r * 8][tx] = cvt_one(src, (int)o, f);
    }
    __syncthreads();
    #pragma unroll
    for (int r = 0; r < 4; ++r) {
        int n = n0 + ty + r * 8;
        dst[(size_t)n * K + k0 + tx] = f2bf(tile[tx][ty + r * 8]);
    }
}

// ---------------------------------------------------------------------------
// MFMA GEMM: 128x128 tile, BK=64, XOR k-slot swizzle; swap per R9 evidence.
// ---------------------------------------------------------------------------
__global__ __launch_bounds__(256) void gemm128(
    const ushort* __restrict__ A, int lda,
    const ushort* __restrict__ Wt,
    const float* __restrict__ bias,
    const ushort* __restrict__ resb,
    ushort* __restrict__ outb, float* __restrict__ outf,
    const int* __restrict__ dtflag,
    int N, int K, int act, int klen, float* __restrict__ psum, int swap)
{
    __shared__ __align__(16) ushort As[128 * 64];
    __shared__ __align__(16) ushort Bs[128 * 64];

    const int tid  = threadIdx.x;
    const int wave = tid >> 6;
    const int lane = tid & 63;
    const int wm = (wave >> 1) * 64;
    const int wn = (wave & 1) * 64;
    const int fm = lane & 15;
    const int quad = lane >> 4;
    const int m0 = (swap ? blockIdx.x : blockIdx.y) * 128;
    const int n0 = (swap ? blockIdx.y : blockIdx.x) * 128;

    floatx4 acc[4][4];
    #pragma unroll
    for (int i = 0; i < 4; ++i)
        #pragma unroll
        for (int j = 0; j < 4; ++j) acc[i][j] = (floatx4){0.f, 0.f, 0.f, 0.f};

    int rowv[4], kgv[4];
    #pragma unroll
    for (int j = 0; j < 4; ++j) {
        int c = wave * 256 + j * 64 + lane;
        rowv[j] = c >> 3;
        kgv[j]  = (((c & 7) ^ ((c >> 3) & 7))) * 8;
    }

    const int kbeg = psum ? (blockIdx.z * klen) : 0;
    const int kend = kbeg + klen;

    for (int k0 = kbeg; k0 < kend; k0 += 64) {
        #pragma unroll
        for (int j = 0; j < 4; ++j)
            gld_lds16(A  + (size_t)(m0 + rowv[j]) * lda + k0 + kgv[j],
                      &As[(wave * 256 + j * 64) * 8]);
        #pragma unroll
        for (int j = 0; j < 4; ++j)
            gld_lds16(Wt + (size_t)(n0 + rowv[j]) * K   + k0 + kgv[j],
                      &Bs[(wave * 256 + j * 64) * 8]);
        __syncthreads();

        #pragma unroll
        for (int h = 0; h < 2; ++h) {
            short8 af[4], bf[4];
            #pragma unroll
            for (int i = 0; i < 4; ++i) {
                int row = wm + i * 16 + fm;
                int slot = (h * 4 + quad) ^ (row & 7);
                af[i] = *(const short8*)&As[row * 64 + slot * 8];
            }
            #pragma unroll
            for (int j = 0; j < 4; ++j) {
                int row = wn + j * 16 + fm;
                int slot = (h * 4 + quad) ^ (row & 7);
                bf[j] = *(const short8*)&Bs[row * 64 + slot * 8];
            }
            #pragma unroll
            for (int i = 0; i < 4; ++i)
                #pragma unroll
                for (int j = 0; j < 4; ++j)
                    acc[i][j] = __builtin_amdgcn_mfma_f32_16x16x32_bf16(af[i], bf[j], acc[i][j], 0, 0, 0);
        }
        __syncthreads();
    }

    if (psum) {
        int mgrid = swap ? gridDim.x : gridDim.y;
        float* po = psum + (size_t)blockIdx.z * ((size_t)mgrid * 128) * N;
        #pragma unroll
        for (int j = 0; j < 4; ++j) {
            int col = n0 + wn + j * 16 + fm;
            #pragma unroll
            for (int i = 0; i < 4; ++i) {
                int rowb = m0 + wm + i * 16 + quad * 4;
                #pragma unroll
                for (int r = 0; r < 4; ++r)
                    po[(size_t)(rowb + r) * N + col] = acc[i][j][r];
            }
        }
        return;
    }

    const int flagv = dtflag ? *dtflag : 0;
    #pragma unroll
    for (int j = 0; j < 4; ++j) {
        int col = n0 + wn + j * 16 + fm;
        float bvv = bias ? bias[col] : 0.f;
        #pragma unroll
        for (int i = 0; i < 4; ++i) {
            int rowb = m0 + wm + i * 16 + quad * 4;
            #pragma unroll
            for (int r = 0; r < 4; ++r) {
                float v = acc[i][j][r] + bvv;
                if (act == 1)
                    v = fmaxf(v, 0.f) + __logf(1.f + __expf(-fabsf(v)));
                size_t o = (size_t)(rowb + r) * N + col;
                if (resb) v += bf2f(resb[o]);
                if (dtflag) {
                    if (flagv) outf[o] = v; else outb[o] = f2bf(v);
                } else {
                    if (outb) outb[o] = f2bf(v);
                    if (outf) outf[o] = v;
                }
            }
        }
    }
}

// ---------------------------------------------------------------------------
// combine split-K partials (4096 x 128 padded) -> xdbl bf16 (stride 96).
// ---------------------------------------------------------------------------
__global__ __launch_bounds__(256) void combine_xdbl(
    const float* __restrict__ psum, ushort* __restrict__ xdbl)
{
    int idx = blockIdx.x * 256 + threadIdx.x;
    int row = idx / 96, col = idx - row * 96;
    float s = 0.f;
    #pragma unroll
    for (int z = 0; z < 8; ++z)
        s += psum[(size_t)z * 4096 * 128 + row * 128 + col];
    xdbl[idx] = f2bf(s);
}

// ---------------------------------------------------------------------------
// Flash MQA attention, split-KV, static-max softmax.
// R13: __expf restored (exp2f is a libm path — R10 vs R12 A/B: VALUBusy
// 35->42%, +6 us); f2bf now native cvt.
// ---------------------------------------------------------------------------
__global__ __launch_bounds__(256) void flash_attn_split(
    const ushort* __restrict__ qkv, ushort* __restrict__ att,
    ushort* __restrict__ partO, float* __restrict__ partL)
{
    __shared__ __align__(16) ushort Ks[64 * 72];
    __shared__ __align__(16) ushort Vt[64 * 72];
    __shared__ __align__(16) ushort Ps[4][32 * 72];

    const int tile = blockIdx.x;
    const int hg   = blockIdx.y;
    const int zz   = blockIdx.z;
    const int b = zz >> 2, s = zz & 3;
    const int q0 = tile * 32;
    const int nkv = (q0 >> 6) + 1;
    const int nsplit = (nkv + SPLIT_KT - 1) / SPLIT_KT;
    if (s >= nsplit) return;
    const int kt0 = s * SPLIT_KT;
    const int kt1 = (nkv < kt0 + SPLIT_KT) ? nkv : (kt0 + SPLIT_KT);

    const int tid  = threadIdx.x;
    const int wave = tid >> 6;
    const int lane = tid & 63;
    const int fm   = lane & 15;
    const int quad = lane >> 4;
    const int h    = hg * 4 + wave;

    const int srow = tid >> 3;
    const int scol = (tid & 7) * 8;
    const int vsw  = (tid & 7) << 3;

    short8 qf[2][2];
    #pragma unroll
    for (int i = 0; i < 2; ++i)
        #pragma unroll
        for (int kh = 0; kh < 2; ++kh)
            qf[i][kh] = *(const short8*)(qkv +
                (size_t)(b * L_SEQ + q0 + i * 16 + fm) * 1152 + h * HD + kh * 32 + quad * 8);

    floatx4 acc[2][4];
    float l_part[2][4];
    #pragma unroll
    for (int i = 0; i < 2; ++i) {
        #pragma unroll
        for (int j = 0; j < 4; ++j) acc[i][j] = (floatx4){0.f, 0.f, 0.f, 0.f};
        #pragma unroll
        for (int r = 0; r < 4; ++r) l_part[i][r] = 0.f;
    }

    for (int kt = kt0; kt < kt1; ++kt) {
        const int kv0 = kt * 64;
        __syncthreads();
        #pragma unroll
        for (int pass = 0; pass < 2; ++pass) {
            int row = srow + pass * 32;
            const ushort* kp = qkv + (size_t)(b * L_SEQ + kv0 + row) * 1152 + NDIM + scol;
            *(short8*)&Ks[row * 72 + scol] = *(const short8*)kp;
            short8 t = *(const short8*)(kp + HD);
            int mw = row ^ vsw;
            #pragma unroll
            for (int i2 = 0; i2 < 8; ++i2) Vt[(scol + i2) * 72 + mw] = (ushort)t[i2];
        }
        __syncthreads();

        floatx4 sp[2][4];
        #pragma unroll
        for (int j = 0; j < 4; ++j) {
            short8 kf0 = *(const short8*)&Ks[(j * 16 + fm) * 72 + quad * 8];
            short8 kf1 = *(const short8*)&Ks[(j * 16 + fm) * 72 + 32 + quad * 8];
            #pragma unroll
            for (int i = 0; i < 2; ++i) {
                floatx4 z = (floatx4){0.f, 0.f, 0.f, 0.f};
                z = __builtin_amdgcn_mfma_f32_16x16x32_bf16(qf[i][0], kf0, z, 0, 0, 0);
                z = __builtin_amdgcn_mfma_f32_16x16x32_bf16(qf[i][1], kf1, z, 0, 0, 0);
                sp[i][j] = z;
            }
        }

        const bool diag = (kt == nkv - 1);
        #pragma unroll
        for (int i = 0; i < 2; ++i)
            #pragma unroll
            for (int j = 0; j < 4; ++j) {
                int col = kv0 + j * 16 + fm;
                #pragma unroll
                for (int r = 0; r < 4; ++r) {
                    float p = __expf(sp[i][j][r] * 0.125f);
                    if (diag) {
                        int rowg = q0 + i * 16 + quad * 4 + r;
                        if (col > rowg) p = 0.f;
                    }
                    sp[i][j][r] = p;
                    l_part[i][r] += p;
                }
            }

        #pragma unroll
        for (int i = 0; i < 2; ++i)
            #pragma unroll
            for (int j = 0; j < 4; ++j)
                #pragma unroll
                for (int r = 0; r < 4; ++r)
                    Ps[wave][(i * 16 + quad * 4 + r) * 72 + j * 16 + fm] = f2bf(sp[i][j][r]);

        short8 pf[2][2];
        #pragma unroll
        for (int i = 0; i < 2; ++i) {
            pf[i][0] = *(const short8*)&Ps[wave][(i * 16 + fm) * 72 + quad * 8];
            pf[i][1] = *(const short8*)&Ps[wave][(i * 16 + fm) * 72 + 32 + quad * 8];
        }

        #pragma unroll
        for (int dj = 0; dj < 4; ++dj) {
            int d = dj * 16 + fm;
            int sw8 = ((d >> 3) & 7) << 3;
            short8 vf0 = *(const short8*)&Vt[d * 72 + ((quad * 8) ^ sw8)];
            short8 vf1 = *(const short8*)&Vt[d * 72 + ((32 + quad * 8) ^ sw8)];
            #pragma unroll
            for (int i = 0; i < 2; ++i) {
                acc[i][dj] = __builtin_amdgcn_mfma_f32_16x16x32_bf16(pf[i][0], vf0, acc[i][dj], 0, 0, 0);
                acc[i][dj] = __builtin_amdgcn_mfma_f32_16x16x32_bf16(pf[i][1], vf1, acc[i][dj], 0, 0, 0);
            }
        }
    }

    float l_red[2][4];
    #pragma unroll
    for (int i = 0; i < 2; ++i)
        #pragma unroll
        for (int r = 0; r < 4; ++r) {
            float rs = l_part[i][r];
            rs += __shfl_xor(rs, 1, 16);
            rs += __shfl_xor(rs, 2, 16);
            rs += __shfl_xor(rs, 4, 16);
            rs += __shfl_xor(rs, 8, 16);
            l_red[i][r] = rs;
        }

    if (nsplit == 1) {
        #pragma unroll
        for (int i = 0; i < 2; ++i) {
            float inv[4];
            #pragma unroll
            for (int r = 0; r < 4; ++r) inv[r] = 1.f / l_red[i][r];
            #pragma unroll
            for (int dj = 0; dj < 4; ++dj)
                #pragma unroll
                for (int r = 0; r < 4; ++r) {
                    int q = q0 + i * 16 + quad * 4 + r;
                    att[(size_t)(b * L_SEQ + q) * NDIM + h * HD + dj * 16 + fm] =
                        f2bf(acc[i][dj][r] * inv[r]);
                }
        }
    } else {
        size_t pbase = ((size_t)((s * 2 + b) * 16 + h)) * L_SEQ;
        #pragma unroll
        for (int i = 0; i < 2; ++i)
            #pragma unroll
            for (int dj = 0; dj < 4; ++dj)
                #pragma unroll
                for (int r = 0; r < 4; ++r) {
                    int q = q0 + i * 16 + quad * 4 + r;
                    partO[(pbase + q) * 64 + dj * 16 + fm] = f2bf(acc[i][dj][r]);
                }
        if (fm == 0) {
            #pragma unroll
            for (int i = 0; i < 2; ++i)
                #pragma unroll
                for (int r = 0; r < 4; ++r)
                    partL[pbase + q0 + i * 16 + quad * 4 + r] = l_red[i][r];
        }
    }
}

// ---------------------------------------------------------------------------
// combine attention split partials for q >= 512.
// ---------------------------------------------------------------------------
__global__ __launch_bounds__(256) void attn_combine(
    const ushort* __restrict__ partO, const float* __restrict__ partL,
    ushort* __restrict__ att)
{
    int gid = blockIdx.x * 256 + threadIdx.x;
    int t8 = gid & 7;
    int row = gid >> 3;
    int q  = 512 + (row % 1536);
    int bh = row / 1536;
    int b = bh >> 4, h = bh & 15;
    int nsplit = (((q >> 5) >> 1) + 1 + SPLIT_KT - 1) / SPLIT_KT;

    float sum[8] = {0.f, 0.f, 0.f, 0.f, 0.f, 0.f, 0.f, 0.f};
    float L = 0.f;
    for (int s = 0; s < nsplit; ++s) {
        size_t pbase = ((size_t)((s * 2 + b) * 16 + h)) * L_SEQ + q;
        L += partL[pbase];
        short8 o = *(const short8*)&partO[pbase * 64 + t8 * 8];
        #pragma unroll
        for (int k = 0; k < 8; ++k) sum[k] += bf2f((ushort)o[k]);
    }
    float inv = 1.f / L;
    short8 outv;
    #pragma unroll
    for (int k = 0; k < 8; ++k) outv[k] = (short)f2bf(sum[k] * inv);
    *(short8*)&att[((size_t)(b * L_SEQ + q)) * NDIM + h * HD + t8 * 8] = outv;
}

// ---------------------------------------------------------------------------
// depthwise conv (window 4, left pad 3) + bias + silu.
// ---------------------------------------------------------------------------
__global__ __launch_bounds__(256) void conv_silu(
    const ushort* __restrict__ xr, const float* __restrict__ conv_w,
    const float* __restrict__ conv_b, ushort* __restrict__ u)
{
    const int idx = blockIdx.x * 256 + threadIdx.x;
    const int c  = idx & (DINNER - 1);
    const int bl = idx >> 11;
    const int l  = bl & (L_SEQ - 1);

    float acc = conv_b[c];
    #pragma unroll
    for (int j = 0; j < DCONV; ++j) {
        int ls = l - 3 + j;
        if (ls >= 0)
            acc += bf2f(xr[(size_t)(bl - 3 + j) * (2 * DINNER) + c]) * conv_w[c * DCONV + j];
    }
    u[idx] = f2bf(silu_f(acc));
}

// ---------------------------------------------------------------------------
// Chunked selective scan, phase 1.
// ---------------------------------------------------------------------------
__global__ __launch_bounds__(256) void scan_phase1(
    const ushort* __restrict__ delta, const ushort* __restrict__ u,
    const ushort* __restrict__ xdbl, const float* __restrict__ A_log,
    float* __restrict__ Hend, float* __restrict__ Sdt)
{
    const int idx = blockIdx.x * 256 + threadIdx.x;
    const int d = idx & (DINNER - 1);
    const int b = (idx >> 11) & (BATCH - 1);
    const int c = idx >> 12;

    float Av[DSTATE], h[DSTATE];
    #pragma unroll
    for (int n = 0; n < DSTATE; ++n) {
        Av[n] = -__expf(A_log[d * DSTATE + n]);
        h[n] = 0.f;
    }

    const int t0 = c * CHUNK;
    size_t bd = ((size_t)b * L_SEQ + t0) * DINNER + d;
    size_t bx = ((size_t)b * L_SEQ + t0) * 96 + DTRANK;
    float sdt = 0.f;

    for (int t = 0; t < CHUNK; ++t) {
        float dt = bf2f(delta[bd]);
        float uv = bf2f(u[bd]);
        sdt += dt;
        float du = dt * uv;
        short8 B0 = *(const short8*)&xdbl[bx];
        short8 B1 = *(const short8*)&xdbl[bx + 8];
        #pragma unroll
        for (int n = 0; n < 8; ++n)
            h[n] = __expf(dt * Av[n]) * h[n] + du * bf2f((ushort)B0[n]);
        #pragma unroll
        for (int n = 0; n < 8; ++n)
            h[8 + n] = __expf(dt * Av[8 + n]) * h[8 + n] + du * bf2f((ushort)B1[n]);
        bd += DINNER; bx += 96;
    }

    size_t ho = (((size_t)c * BATCH + b) * DINNER + d) * DSTATE;
    #pragma unroll
    for (int n = 0; n < DSTATE; n += 4)
        *(floatx4*)&Hend[ho + n] = (floatx4){h[n], h[n + 1], h[n + 2], h[n + 3]};
    Sdt[((size_t)c * BATCH + b) * DINNER + d] = sdt;
}

// ---------------------------------------------------------------------------
// phase 2: in-place exclusive combine over 64 chunks.
// ---------------------------------------------------------------------------
__global__ __launch_bounds__(256) void scan_phase2(
    float* __restrict__ H, const float* __restrict__ Sdt,
    const float* __restrict__ A_log)
{
    const int idx = blockIdx.x * 256 + threadIdx.x;
    const int n = idx & (DSTATE - 1);
    const int d = (idx >> 4) & (DINNER - 1);
    const int b = idx >> 15;

    const float Av = -__expf(A_log[d * DSTATE + n]);
    float hin = 0.f;
    for (int c = 0; c < NCHUNK; ++c) {
        size_t o  = (((size_t)c * BATCH + b) * DINNER + d) * DSTATE + n;
        float e   = H[o];
        float dAc = __expf(Av * Sdt[((size_t)c * BATCH + b) * DINNER + d]);
        H[o] = hin;
        hin = dAc * hin + e;
    }
}

// ---------------------------------------------------------------------------
// phase 3: redo chunk scan from Hin, emit y, fused ymod.
// ---------------------------------------------------------------------------
__global__ __launch_bounds__(256) void scan_phase3(
    const ushort* __restrict__ delta, const ushort* __restrict__ u,
    const ushort* __restrict__ xdbl, const float* __restrict__ A_log,
    const float* __restrict__ Hin, const float* __restrict__ Dp,
    const ushort* __restrict__ xr, ushort* __restrict__ yb)
{
    const int idx = blockIdx.x * 256 + threadIdx.x;
    const int d = idx & (DINNER - 1);
    const int b = (idx >> 11) & (BATCH - 1);
    const int c = idx >> 12;

    float Av[DSTATE], h[DSTATE];
    size_t ho = (((size_t)c * BATCH + b) * DINNER + d) * DSTATE;
    #pragma unroll
    for (int n = 0; n < DSTATE; n += 4) {
        floatx4 hv = *(const floatx4*)&Hin[ho + n];
        h[n] = hv[0]; h[n + 1] = hv[1]; h[n + 2] = hv[2]; h[n + 3] = hv[3];
    }
    #pragma unroll
    for (int n = 0; n < DSTATE; ++n)
        Av[n] = -__expf(A_log[d * DSTATE + n]);

    const float Dpd = Dp[d];
    const int t0 = c * CHUNK;
    size_t bd = ((size_t)b * L_SEQ + t0) * DINNER + d;
    size_t bx = ((size_t)b * L_SEQ + t0) * 96 + DTRANK;
    size_t br = ((size_t)b * L_SEQ + t0) * (2 * DINNER) + DINNER + d;

    for (int t = 0; t < CHUNK; ++t) {
        float dt = bf2f(delta[bd]);
        float uv = bf2f(u[bd]);
        float du = dt * uv;
        short8 B0 = *(const short8*)&xdbl[bx];
        short8 B1 = *(const short8*)&xdbl[bx + 8];
        short8 C0 = *(const short8*)&xdbl[bx + 16];
        short8 C1 = *(const short8*)&xdbl[bx + 24];
        float y = 0.f;
        #pragma unroll
        for (int n = 0; n < 8; ++n) {
            h[n] = __expf(dt * Av[n]) * h[n] + du * bf2f((ushort)B0[n]);
            y += h[n] * bf2f((ushort)C0[n]);
        }
        #pragma unroll
        for (int n = 0; n < 8; ++n) {
            h[8 + n] = __expf(dt * Av[8 + n]) * h[8 + n] + du * bf2f((ushort)B1[n]);
            y += h[8 + n] * bf2f((ushort)C1[n]);
        }
        float yv = y + uv * Dpd;
        float r  = bf2f(xr[br]);
        yb[bd] = f2bf(yv * silu_f(r));
        bd += DINNER; bx += 96; br += 2 * DINNER;
    }
}

// ---------------------------------------------------------------------------
extern "C" void kernel_launch(void* const* d_in, const int* in_sizes, int n_in,
                              void* d_out, int out_size, void* d_ws, size_t ws_size,
                              hipStream_t stream) {
    const void* x_raw      = d_in[0];
    const void* wqkv_raw   = d_in[1];
    const void* bqkv_raw   = d_in[2];
    const void* wao_raw    = d_in[3];
    const void* bao_raw    = d_in[4];
    const void* win_raw    = d_in[5];
    const void* convw_raw  = d_in[6];
    const void* convb_raw  = d_in[7];
    const void* wxp_raw    = d_in[8];
    const void* wdt_raw    = d_in[9];
    const void* bdt_raw    = d_in[10];
    const void* Alog_raw   = d_in[11];
    const void* Dp_raw     = d_in[12];
    const void* wout_raw   = d_in[13];

    const int M = BATCH * L_SEQ;  // 4096

    char* p = (char*)d_ws;
    size_t off = 0;
    auto A_ = [&](size_t bytes) { void* q = p + off; off += (bytes + 255) & ~255ull; return q; };

    ushort* x_b    = (ushort*)A_((size_t)M * NDIM * 2);
    ushort* wqkv_t = (ushort*)A_((size_t)NDIM * 1152 * 2);
    ushort* wao_t  = (ushort*)A_((size_t)NDIM * NDIM * 2);
    ushort* win_t  = (ushort*)A_((size_t)NDIM * 4096 * 2);
    float*  psum   = (float*)x_b;
    ushort* yb     = x_b;
    float*  Sdt    = (float*)(x_b + (size_t)M * DINNER);

    ushort* qkv    = (ushort*)A_((size_t)M * 1152 * 2);
    ushort* att    = (ushort*)A_((size_t)M * NDIM * 2);
    float*  Hend   = (float*)qkv;

    ushort* delta_b = (ushort*)A_((size_t)M * DINNER * 2);

    ushort* wxp_t  = (ushort*)A_((size_t)128 * DINNER * 2);
    ushort* wdt_t  = (ushort*)A_((size_t)DTRANK * DINNER * 2);
    ushort* wout_t = (ushort*)A_((size_t)DINNER * NDIM * 2);
    float*  bqkv_f = (float*)A_(1152 * 4);
    float*  bao_f  = (float*)A_(NDIM * 4);
    float*  convw_f= (float*)A_((size_t)DINNER * DCONV * 4);
    float*  convb_f= (float*)A_(DINNER * 4);
    float*  bdt_f  = (float*)A_(DINNER * 4);
    float*  Alog_f = (float*)A_((size_t)DINNER * DSTATE * 4);
    float*  Dp_f   = (float*)A_(DINNER * 4);
    int*    flag   = (int*)A_(256);
    ushort* x1b    = (ushort*)A_((size_t)M * NDIM * 2);
    ushort* xr     = (ushort*)A_((size_t)M * 4096 * 2);
    ushort* u      = (ushort*)A_((size_t)M * DINNER * 2);
    ushort* xdbl   = (ushort*)A_((size_t)M * 96 * 2);

    ushort* partO = xr;
    float*  partL = (float*)u;

    dim3 blk(256);

    // 0. one-launch prep (probe + x cvt + 6 transposes + pad + small params)
    prep_kernel<<<dim3(25473), blk, 0, stream>>>(
        x_raw, wqkv_raw, wao_raw, win_raw, wxp_raw, wdt_raw, wout_raw,
        bqkv_raw, bao_raw, convw_raw, convb_raw, bdt_raw, Alog_raw, Dp_raw,
        x_b, wqkv_t, wao_t, win_t, wxp_t, wdt_t, wout_t,
        bqkv_f, bao_f, convw_f, convb_f, bdt_f, Alog_f, Dp_f, flag);

    // 1. qkv = x @ wqkv + bqkv   (swap=0)
    gemm128<<<dim3(1152 / 128, M / 128), blk, 0, stream>>>(
        x_b, NDIM, wqkv_t, bqkv_f, nullptr, qkv, nullptr, nullptr, 1152, NDIM, 0, NDIM, nullptr, 0);

    // 2. flash attention (split-KV) + combine
    flash_attn_split<<<dim3(L_SEQ / 32, NHEADS / 4, BATCH * 4), blk, 0, stream>>>(
        qkv, att, partO, partL);
    attn_combine<<<dim3(1536), blk, 0, stream>>>(partO, partL, att);

    // 3. x1 = att @ w_ao + b_ao + x   (swap=0)
    gemm128<<<dim3(NDIM / 128, M / 128), blk, 0, stream>>>(
        att, NDIM, wao_t, bao_f, x_b, x1b, nullptr, nullptr, NDIM, NDIM, 0, NDIM, nullptr, 0);

    // 4. xr = x1 @ w_in   (swap=1: XCD-local A-strip)
    gemm128<<<dim3(M / 128, 4096 / 128), blk, 0, stream>>>(
        x1b, NDIM, win_t, nullptr, nullptr, xr, nullptr, nullptr, 4096, NDIM, 0, NDIM, nullptr, 1);

    // 5. conv + silu -> u
    conv_silu<<<dim3(M * DINNER / 256), blk, 0, stream>>>(xr, convw_f, convb_f, u);

    // 6. xdbl = u @ w_xproj  (split-K=8 over padded N=128)
    gemm128<<<dim3(1, M / 128, 8), blk, 0, stream>>>(
        u, DINNER, wxp_t, nullptr, nullptr, nullptr, nullptr, nullptr, 128, DINNER, 0, DINNER / 8, psum, 0);
    combine_xdbl<<<dim3(M * 96 / 256), blk, 0, stream>>>(psum, xdbl);

    // 7. delta = softplus(xdbl[:, :64] @ w_dt + b_dt)  (swap=0)
    gemm128<<<dim3(DINNER / 128, M / 128), blk, 0, stream>>>(
        xdbl, 96, wdt_t, bdt_f, nullptr, delta_b, nullptr, nullptr, DINNER, DTRANK, 1, DTRANK, nullptr, 0);

    // 8. chunked selective scan (+fused ymod) -> yb
    scan_phase1<<<dim3(NCHUNK * BATCH * DINNER / 256), blk, 0, stream>>>(
        delta_b, u, xdbl, Alog_f, Hend, Sdt);
    scan_phase2<<<dim3(BATCH * DINNER * DSTATE / 256), blk, 0, stream>>>(
        Hend, Sdt, Alog_f);
    scan_phase3<<<dim3(NCHUNK * BATCH * DINNER / 256), blk, 0, stream>>>(
        delta_b, u, xdbl, Alog_f, Hend, Dp_f, xr, yb);

    // 10. out = yb @ w_out + x1  (swap=1)
    gemm128<<<dim3(M / 128, NDIM / 128), blk, 0, stream>>>(
        yb, DINNER, wout_t, nullptr, x1b, (ushort*)d_out, (float*)d_out, flag, NDIM, DINNER, 0, DINNER, nullptr, 1);
}